// Round 16
// baseline (309.704 us; speedup 1.0000x reference)
//
#include <hip/hip_runtime.h>
#include <hip/hip_bf16.h>
#include <math.h>

#define NN 50000
#define NE 800000
#define ET 850000      // NE + NN self loops
#define NG 64

// bucket partition geometry
#define NBUK 125       // buckets
#define BS   400       // nodes per bucket (125*400 = 50000)
#define CHK  8192      // edges per chunk
#define NCH  104       // ceil(ET/CHK)
#define NHIST (NBUK * NCH)          // 13000
#define NSB  ((NHIST + 255) / 256)  // 51 scan blocks

// ---------------- CSR build: bucket-partitioned ----------------

__global__ __launch_bounds__(256) void hist_k(const int* __restrict__ ei,
                                              int* __restrict__ ghist) {
    __shared__ int h[NBUK];
    int c = blockIdx.x, t = threadIdx.x;
    for (int i = t; i < NBUK; i += 256) h[i] = 0;
    __syncthreads();
    int e0 = c * CHK;
    int e1 = min(ET, e0 + CHK);
    for (int e = e0 + t; e < e1; e += 256) {
        int dst = (e < NE) ? ei[NE + e] : (e - NE);
        atomicAdd(&h[dst / BS], 1);
    }
    __syncthreads();
    for (int b = t; b < NBUK; b += 256) ghist[b * NCH + c] = h[b];
}

// generic hierarchical exclusive scan (n elements) — partial + block sums
__global__ __launch_bounds__(256) void gscan1_k(const int* __restrict__ in,
                                                int* __restrict__ out,
                                                int* __restrict__ bsum, int n) {
    int t = threadIdx.x;
    int idx = blockIdx.x * 256 + t;
    int v = (idx < n) ? in[idx] : 0;
    int lane = t & 63, wave = t >> 6;
    int inc = v;
#pragma unroll
    for (int d = 1; d < 64; d <<= 1) {
        int u = __shfl_up(inc, d);
        if (lane >= d) inc += u;
    }
    __shared__ int wtot[4];
    if (lane == 63) wtot[wave] = inc;
    __syncthreads();
    int wpre = 0;
    for (int w = 0; w < wave; w++) wpre += wtot[w];
    if (idx < n) out[idx] = wpre + inc - v;
    if (t == 255) bsum[blockIdx.x] = wpre + inc;
}

__global__ __launch_bounds__(256) void gscan2_k(const int* __restrict__ bsum,
                                                int* __restrict__ bpre, int nb,
                                                int* __restrict__ tailp, int tailv) {
    int t = threadIdx.x;
    int v = (t < nb) ? bsum[t] : 0;
    int lane = t & 63, wave = t >> 6;
    int inc = v;
#pragma unroll
    for (int d = 1; d < 64; d <<= 1) {
        int u = __shfl_up(inc, d);
        if (lane >= d) inc += u;
    }
    __shared__ int wtot[4];
    if (lane == 63) wtot[wave] = inc;
    __syncthreads();
    int wpre = 0;
    for (int w = 0; w < wave; w++) wpre += wtot[w];
    if (t < nb) bpre[t] = wpre + inc - v;
    if (t == 0 && tailp) *tailp = tailv;
}

// partition edges into bucket regions: packed = (dstLocal<<17) | src
__global__ __launch_bounds__(256) void part_k(const int* __restrict__ ei,
                                              const int* __restrict__ gbase,
                                              const int* __restrict__ bpre,
                                              int* __restrict__ packed) {
    __shared__ int cur[NBUK];
    __shared__ int baseL[NBUK];
    int c = blockIdx.x, t = threadIdx.x;
    for (int i = t; i < NBUK; i += 256) {
        int idx = i * NCH + c;
        cur[i] = 0;
        baseL[i] = gbase[idx] + bpre[idx >> 8];
    }
    __syncthreads();
    int e0 = c * CHK;
    int e1 = min(ET, e0 + CHK);
    for (int e = e0 + t; e < e1; e += 256) {
        int src, dst;
        if (e < NE) { src = ei[e]; dst = ei[NE + e]; }
        else        { src = dst = e - NE; }
        int b = dst / BS;
        int r = atomicAdd(&cur[b], 1);
        packed[baseL[b] + r] = ((dst - b * BS) << 17) | src;
    }
}

// per-bucket counting sort -> offsets + csr
__global__ __launch_bounds__(256) void csr_k(const int* __restrict__ packed,
                                             const int* __restrict__ gbase,
                                             const int* __restrict__ bpre,
                                             int* __restrict__ csr,
                                             int* __restrict__ offsets) {
    __shared__ int cnt[BS];
    __shared__ int sc[2][512];
    __shared__ int cur[BS];
    __shared__ int Ss, Ts;
    int b = blockIdx.x, t = threadIdx.x;
    for (int i = t; i < BS; i += 256) cnt[i] = 0;
    if (t == 0) {
        int i0 = b * NCH;
        Ss = gbase[i0] + bpre[i0 >> 8];
        int i1 = (b + 1) * NCH;
        Ts = (b == NBUK - 1) ? ET : (gbase[i1] + bpre[i1 >> 8]);
    }
    __syncthreads();
    int n0 = Ss, n1 = Ts;
    for (int i = n0 + t; i < n1; i += 256) {
        int p = packed[i];
        atomicAdd(&cnt[p >> 17], 1);
    }
    __syncthreads();
    for (int i = t; i < 512; i += 256) sc[0][i] = (i < BS) ? cnt[i] : 0;
    __syncthreads();
    int pp = 0;
    for (int d = 1; d < 512; d <<= 1) {
        for (int i = t; i < 512; i += 256) {
            int v = sc[pp][i];
            if (i >= d) v += sc[pp][i - d];
            sc[pp ^ 1][i] = v;
        }
        pp ^= 1;
        __syncthreads();
    }
    for (int i = t; i < BS; i += 256) {
        int pre = (i == 0) ? 0 : sc[pp][i - 1];
        offsets[b * BS + i] = Ss + pre;
        cur[i] = Ss + pre;
    }
    __syncthreads();
    for (int i = n0 + t; i < n1; i += 256) {
        int p = packed[i];
        int pos = atomicAdd(&cur[p >> 17], 1);
        csr[pos] = p & 0x1FFFF;
    }
}

// deterministic order: one WAVE per node, bitonic sort across 64 lanes.
__global__ __launch_bounds__(256) void sortw_k(const int* __restrict__ offsets,
                                               int* __restrict__ csr) {
    int gt = blockIdx.x * blockDim.x + threadIdx.x;
    int n = gt >> 6;
    int lane = gt & 63;
    if (n >= NN) return;
    int b0 = offsets[n], b1 = offsets[n + 1];
    int deg = b1 - b0;
    if (deg <= 1) return;
    if (deg <= 64) {
        int v = (lane < deg) ? csr[b0 + lane] : 0x7FFFFFFF;
#pragma unroll
        for (int k = 2; k <= 64; k <<= 1) {
#pragma unroll
            for (int j = k >> 1; j > 0; j >>= 1) {
                int partner = __shfl_xor(v, j);
                bool up = ((lane & k) == 0);
                bool keepmin = (((lane & j) == 0) == up);
                v = keepmin ? min(v, partner) : max(v, partner);
            }
        }
        if (lane < deg) csr[b0 + lane] = v;
    } else if (lane == 0) {
        for (int i = b0 + 1; i < b1; i++) {
            int v = csr[i];
            int j = i - 1;
            while (j >= b0 && csr[j] > v) { csr[j + 1] = csr[j]; j--; }
            csr[j + 1] = v;
        }
    }
}

// ---------------- layer-1 alS/alD ----------------

__global__ __launch_bounds__(256) void feat1b_k(const float* __restrict__ x,
                                                const float* __restrict__ w1,
                                                const float* __restrict__ as1,
                                                const float* __restrict__ ad1,
                                                float* __restrict__ alS,
                                                float* __restrict__ alD) {
    int t = threadIdx.x;
    int tt = t & 127;
    int n = blockIdx.x * 2 + (t >> 7);
    float x0 = x[n * 2 + 0], x1 = x[n * 2 + 1];
    float v = x0 * w1[tt] + x1 * w1[128 + tt];
    int head = (t >> 6) & 1, lane = t & 63;
    float ps = v * as1[tt];
    float pd = v * ad1[tt];
    for (int d = 32; d; d >>= 1) {
        ps += __shfl_down(ps, d);
        pd += __shfl_down(pd, d);
    }
    if (lane == 0) {
        alS[n * 2 + head] = ps;
        alD[n * 2 + head] = pd;
    }
}

// ---------------- fused layer 1: ONE wave per node, both heads (r14 best) ----------------
// alpha pass gathers x[s] lane-parallel; LDS slot = {w0, w1, x0, x1};
// acc loop is pure LDS + FMA.

__global__ __launch_bounds__(256) void agg1_k(const float2* __restrict__ x2,
                                              const float* __restrict__ w1,
                                              const float* __restrict__ alS,
                                              const float* __restrict__ alD,
                                              const float* __restrict__ bias,
                                              const int* __restrict__ offsets,
                                              const int* __restrict__ csr,
                                              float* __restrict__ out) {
    __shared__ float4 wslds[4][64];
    int t = threadIdx.x;
    int wave = t >> 6, lane = t & 63, grp = lane >> 4, c4 = lane & 15;
    int gl = lane & 15;
    int n = blockIdx.x * 4 + wave;
    int b0 = offsets[n], b1 = offsets[n + 1];
    int deg = b1 - b0;
    float2 adv = ((const float2*)alD)[n];
    const float2* alS2 = (const float2*)alS;

    float4 wa0 = ((const float4*)w1)[c4];
    float4 wa1 = ((const float4*)w1)[16 + c4];
    float4 wb0 = ((const float4*)(w1 + 128))[c4];
    float4 wb1 = ((const float4*)(w1 + 128))[16 + c4];
    float4 acc0 = make_float4(0.f, 0.f, 0.f, 0.f);
    float4 acc1 = make_float4(0.f, 0.f, 0.f, 0.f);
    float inv0, inv1;

    if (deg <= 64) {
        bool valid = lane < deg;
        int s = 0; float ev0 = -1e30f, ev1 = -1e30f;
        float2 xs = make_float2(0.f, 0.f);
        if (valid) {
            s = csr[b0 + lane];
            float2 al = alS2[s];
            xs = x2[s];
            float e0 = al.x + adv.x;
            ev0 = e0 > 0.f ? e0 : 0.2f * e0;
            float e1 = al.y + adv.y;
            ev1 = e1 > 0.f ? e1 : 0.2f * e1;
        }
        float m0 = ev0, m1 = ev1;
#pragma unroll
        for (int d = 32; d; d >>= 1) {
            m0 = fmaxf(m0, __shfl_xor(m0, d));
            m1 = fmaxf(m1, __shfl_xor(m1, d));
        }
        if (valid) {
            float w0 = expf(ev0 - m0);
            float w1v = expf(ev1 - m1);
            wslds[wave][lane] = make_float4(w0, w1v, xs.x, xs.y);
        }
        float ssum0 = 0.f, ssum1 = 0.f;
#pragma unroll
        for (int k = 0; k < 4; k++) {
            int j = gl + 16 * k;
            if (j < deg) {
                float4 f = wslds[wave][j];
                ssum0 += f.x;
                ssum1 += f.y;
            }
        }
        for (int d = 8; d; d >>= 1) {
            ssum0 += __shfl_xor(ssum0, d);
            ssum1 += __shfl_xor(ssum1, d);
        }
        inv0 = 1.f / (ssum0 + 1e-16f);
        inv1 = 1.f / (ssum1 + 1e-16f);
        int j = grp;
        for (; j + 12 < deg; j += 16) {
            float4 f0 = wslds[wave][j];
            float4 f1 = wslds[wave][j + 4];
            float4 f2 = wslds[wave][j + 8];
            float4 f3 = wslds[wave][j + 12];
            float4 v;
            v.x = f0.z * wa0.x + f0.w * wb0.x;
            v.y = f0.z * wa0.y + f0.w * wb0.y;
            v.z = f0.z * wa0.z + f0.w * wb0.z;
            v.w = f0.z * wa0.w + f0.w * wb0.w;
            acc0.x = fmaf(f0.x, v.x, acc0.x);
            acc0.y = fmaf(f0.x, v.y, acc0.y);
            acc0.z = fmaf(f0.x, v.z, acc0.z);
            acc0.w = fmaf(f0.x, v.w, acc0.w);
            v.x = f0.z * wa1.x + f0.w * wb1.x;
            v.y = f0.z * wa1.y + f0.w * wb1.y;
            v.z = f0.z * wa1.z + f0.w * wb1.z;
            v.w = f0.z * wa1.w + f0.w * wb1.w;
            acc1.x = fmaf(f0.y, v.x, acc1.x);
            acc1.y = fmaf(f0.y, v.y, acc1.y);
            acc1.z = fmaf(f0.y, v.z, acc1.z);
            acc1.w = fmaf(f0.y, v.w, acc1.w);
            v.x = f1.z * wa0.x + f1.w * wb0.x;
            v.y = f1.z * wa0.y + f1.w * wb0.y;
            v.z = f1.z * wa0.z + f1.w * wb0.z;
            v.w = f1.z * wa0.w + f1.w * wb0.w;
            acc0.x = fmaf(f1.x, v.x, acc0.x);
            acc0.y = fmaf(f1.x, v.y, acc0.y);
            acc0.z = fmaf(f1.x, v.z, acc0.z);
            acc0.w = fmaf(f1.x, v.w, acc0.w);
            v.x = f1.z * wa1.x + f1.w * wb1.x;
            v.y = f1.z * wa1.y + f1.w * wb1.y;
            v.z = f1.z * wa1.z + f1.w * wb1.z;
            v.w = f1.z * wa1.w + f1.w * wb1.w;
            acc1.x = fmaf(f1.y, v.x, acc1.x);
            acc1.y = fmaf(f1.y, v.y, acc1.y);
            acc1.z = fmaf(f1.y, v.z, acc1.z);
            acc1.w = fmaf(f1.y, v.w, acc1.w);
            v.x = f2.z * wa0.x + f2.w * wb0.x;
            v.y = f2.z * wa0.y + f2.w * wb0.y;
            v.z = f2.z * wa0.z + f2.w * wb0.z;
            v.w = f2.z * wa0.w + f2.w * wb0.w;
            acc0.x = fmaf(f2.x, v.x, acc0.x);
            acc0.y = fmaf(f2.x, v.y, acc0.y);
            acc0.z = fmaf(f2.x, v.z, acc0.z);
            acc0.w = fmaf(f2.x, v.w, acc0.w);
            v.x = f2.z * wa1.x + f2.w * wb1.x;
            v.y = f2.z * wa1.y + f2.w * wb1.y;
            v.z = f2.z * wa1.z + f2.w * wb1.z;
            v.w = f2.z * wa1.w + f2.w * wb1.w;
            acc1.x = fmaf(f2.y, v.x, acc1.x);
            acc1.y = fmaf(f2.y, v.y, acc1.y);
            acc1.z = fmaf(f2.y, v.z, acc1.z);
            acc1.w = fmaf(f2.y, v.w, acc1.w);
            v.x = f3.z * wa0.x + f3.w * wb0.x;
            v.y = f3.z * wa0.y + f3.w * wb0.y;
            v.z = f3.z * wa0.z + f3.w * wb0.z;
            v.w = f3.z * wa0.w + f3.w * wb0.w;
            acc0.x = fmaf(f3.x, v.x, acc0.x);
            acc0.y = fmaf(f3.x, v.y, acc0.y);
            acc0.z = fmaf(f3.x, v.z, acc0.z);
            acc0.w = fmaf(f3.x, v.w, acc0.w);
            v.x = f3.z * wa1.x + f3.w * wb1.x;
            v.y = f3.z * wa1.y + f3.w * wb1.y;
            v.z = f3.z * wa1.z + f3.w * wb1.z;
            v.w = f3.z * wa1.w + f3.w * wb1.w;
            acc1.x = fmaf(f3.y, v.x, acc1.x);
            acc1.y = fmaf(f3.y, v.y, acc1.y);
            acc1.z = fmaf(f3.y, v.z, acc1.z);
            acc1.w = fmaf(f3.y, v.w, acc1.w);
        }
        for (; j < deg; j += 4) {
            float4 f0 = wslds[wave][j];
            float4 v;
            v.x = f0.z * wa0.x + f0.w * wb0.x;
            v.y = f0.z * wa0.y + f0.w * wb0.y;
            v.z = f0.z * wa0.z + f0.w * wb0.z;
            v.w = f0.z * wa0.w + f0.w * wb0.w;
            acc0.x = fmaf(f0.x, v.x, acc0.x);
            acc0.y = fmaf(f0.x, v.y, acc0.y);
            acc0.z = fmaf(f0.x, v.z, acc0.z);
            acc0.w = fmaf(f0.x, v.w, acc0.w);
            v.x = f0.z * wa1.x + f0.w * wb1.x;
            v.y = f0.z * wa1.y + f0.w * wb1.y;
            v.z = f0.z * wa1.z + f0.w * wb1.z;
            v.w = f0.z * wa1.w + f0.w * wb1.w;
            acc1.x = fmaf(f0.y, v.x, acc1.x);
            acc1.y = fmaf(f0.y, v.y, acc1.y);
            acc1.z = fmaf(f0.y, v.z, acc1.z);
            acc1.w = fmaf(f0.y, v.w, acc1.w);
        }
    } else {
        for (int head = 0; head < 2; head++) {
            float ad = head ? adv.y : adv.x;
            float4 wa = head ? wa1 : wa0, wb = head ? wb1 : wb0;
            float m = -1e30f;
            for (int i = b0 + gl; i < b1; i += 16) {
                int s = csr[i];
                float ev = alS[s * 2 + head] + ad;
                ev = ev > 0.f ? ev : 0.2f * ev;
                m = fmaxf(m, ev);
            }
            for (int d = 8; d; d >>= 1) m = fmaxf(m, __shfl_xor(m, d));
            float ssum = 0.f;
            for (int i = b0 + gl; i < b1; i += 16) {
                int s = csr[i];
                float ev = alS[s * 2 + head] + ad;
                ev = ev > 0.f ? ev : 0.2f * ev;
                float w = expf(ev - m);
                ssum += w;
            }
            for (int d = 8; d; d >>= 1) ssum += __shfl_xor(ssum, d);
            float invh = 1.f / (ssum + 1e-16f);
            float4 acc = make_float4(0.f, 0.f, 0.f, 0.f);
            for (int i = b0 + grp; i < b1; i += 4) {
                int s = csr[i];
                float ev = alS[s * 2 + head] + ad;
                ev = ev > 0.f ? ev : 0.2f * ev;
                float w = expf(ev - m);
                float2 xs = x2[s];
                float4 v;
                v.x = xs.x * wa.x + xs.y * wb.x;
                v.y = xs.x * wa.y + xs.y * wb.y;
                v.z = xs.x * wa.z + xs.y * wb.z;
                v.w = xs.x * wa.w + xs.y * wb.w;
                acc.x = fmaf(w, v.x, acc.x);
                acc.y = fmaf(w, v.y, acc.y);
                acc.z = fmaf(w, v.z, acc.z);
                acc.w = fmaf(w, v.w, acc.w);
            }
            if (head == 0) { acc0 = acc; inv0 = invh; }
            else           { acc1 = acc; inv1 = invh; }
        }
    }
#pragma unroll
    for (int mask = 16; mask <= 32; mask <<= 1) {
        acc0.x += __shfl_xor(acc0.x, mask);
        acc0.y += __shfl_xor(acc0.y, mask);
        acc0.z += __shfl_xor(acc0.z, mask);
        acc0.w += __shfl_xor(acc0.w, mask);
        acc1.x += __shfl_xor(acc1.x, mask);
        acc1.y += __shfl_xor(acc1.y, mask);
        acc1.z += __shfl_xor(acc1.z, mask);
        acc1.w += __shfl_xor(acc1.w, mask);
    }
    if (grp < 2) {
        float4 acc = (grp == 0) ? acc0 : acc1;
        float inv = (grp == 0) ? inv0 : inv1;
        float4 b = ((const float4*)bias)[grp * 16 + c4];
        float4 r;
        r.x = acc.x * inv + b.x;
        r.y = acc.y * inv + b.y;
        r.z = acc.z * inv + b.z;
        r.w = acc.w * inv + b.w;
        r.x = r.x > 0.f ? r.x : expm1f(r.x);
        r.y = r.y > 0.f ? r.y : expm1f(r.y);
        r.z = r.z > 0.f ? r.z : expm1f(r.z);
        r.w = r.w > 0.f ? r.w : expm1f(r.w);
        ((float4*)out)[((size_t)n * 2 + grp) * 16 + c4] = r;
    }
}

// ---------------- GEMM + al for layers 2/3: scalar row loads (no rowb LDS) ----------------
// Row pointers are wave-uniform -> forced to SGPR via readfirstlane; row[k] becomes
// s_load (scalar cache pipe), Wl stays LDS. FMA chain unchanged (bit-identical).

__device__ __forceinline__ const float* uniptr(const float* p) {
    uint64_t a = (uint64_t)p;
    uint32_t lo = __builtin_amdgcn_readfirstlane((uint32_t)a);
    uint32_t hi = __builtin_amdgcn_readfirstlane((uint32_t)(a >> 32));
    return (const float*)((((uint64_t)hi) << 32) | lo);
}

template <int K>
__global__ __launch_bounds__(256) void gemm_al_k(const float* __restrict__ in,
                                                 const float* __restrict__ W,
                                                 const float* __restrict__ as,
                                                 const float* __restrict__ ad,
                                                 float* __restrict__ h,
                                                 float* __restrict__ alS,
                                                 float* __restrict__ alD) {
    __shared__ float Wl[K * 64];
    int t = threadIdx.x;
    for (int i = t; i < K * 64; i += 256) Wl[i] = W[i];
    int wave = t >> 6, c = t & 63;
    int nb = blockIdx.x * 16 + wave * 4;
    const float* r0 = uniptr(in + (size_t)(nb + 0) * K);
    const float* r1 = uniptr(in + (size_t)(nb + 1) * K);
    const float* r2 = uniptr(in + (size_t)(nb + 2) * K);
    const float* r3 = uniptr(in + (size_t)(nb + 3) * K);
    __syncthreads();
    float a0 = 0.f, a1 = 0.f, a2 = 0.f, a3 = 0.f;
#pragma unroll 8
    for (int k = 0; k < K; k++) {
        float wv = Wl[k * 64 + c];
        a0 = fmaf(r0[k], wv, a0);
        a1 = fmaf(r1[k], wv, a1);
        a2 = fmaf(r2[k], wv, a2);
        a3 = fmaf(r3[k], wv, a3);
    }
    h[(size_t)(nb + 0) * 64 + c] = a0;
    h[(size_t)(nb + 1) * 64 + c] = a1;
    h[(size_t)(nb + 2) * 64 + c] = a2;
    h[(size_t)(nb + 3) * 64 + c] = a3;
    float asc = as[c], adc = ad[c];
    float ps0 = a0 * asc, pd0 = a0 * adc;
    float ps1 = a1 * asc, pd1 = a1 * adc;
    float ps2 = a2 * asc, pd2 = a2 * adc;
    float ps3 = a3 * asc, pd3 = a3 * adc;
    for (int d = 32; d; d >>= 1) {
        ps0 += __shfl_down(ps0, d); pd0 += __shfl_down(pd0, d);
        ps1 += __shfl_down(ps1, d); pd1 += __shfl_down(pd1, d);
        ps2 += __shfl_down(ps2, d); pd2 += __shfl_down(pd2, d);
        ps3 += __shfl_down(ps3, d); pd3 += __shfl_down(pd3, d);
    }
    if (c == 0) {
        alS[nb + 0] = ps0; alD[nb + 0] = pd0;
        alS[nb + 1] = ps1; alD[nb + 1] = pd1;
        alS[nb + 2] = ps2; alD[nb + 2] = pd2;
        alS[nb + 3] = ps3; alD[nb + 3] = pd3;
    }
}

// ---------------- fused layers 2/3: 64-lane alpha + unroll-4 h4 gather agg (r14 best) ----------------

__global__ __launch_bounds__(256) void aggf2_k(const float4* __restrict__ h4,
                                               const float* __restrict__ alS,
                                               const float* __restrict__ alD,
                                               const float* __restrict__ bias,
                                               const int* __restrict__ offsets,
                                               const int* __restrict__ csr,
                                               float* __restrict__ out) {
    __shared__ float2 wlds[4][64];          // {w, s_bits}
    int t = threadIdx.x;
    int wave = t >> 6, lane = t & 63, grp = lane >> 4, c4 = lane & 15;
    int gl = lane & 15;
    int n = blockIdx.x * 4 + wave;
    int b0 = offsets[n], b1 = offsets[n + 1];
    int deg = b1 - b0;
    float adn = alD[n];

    float4 acc = make_float4(0.f, 0.f, 0.f, 0.f);
    float inv;

    if (deg <= 64) {
        bool valid = lane < deg;
        int s = 0; float ev = -1e30f;
        if (valid) {
            s = csr[b0 + lane];
            float e0 = alS[s] + adn;
            ev = e0 > 0.f ? e0 : 0.2f * e0;
        }
        float m = ev;
#pragma unroll
        for (int d = 32; d; d >>= 1) m = fmaxf(m, __shfl_xor(m, d));
        if (valid) {
            float w = expf(ev - m);
            wlds[wave][lane] = make_float2(w, __int_as_float(s));
        }
        float ssum = 0.f;
#pragma unroll
        for (int k = 0; k < 4; k++) {
            int j = gl + 16 * k;
            if (j < deg) ssum += wlds[wave][j].x;
        }
        for (int d = 8; d; d >>= 1) ssum += __shfl_xor(ssum, d);
        inv = 1.f / (ssum + 1e-16f);
        int j = grp;
        for (; j + 12 < deg; j += 16) {
            float2 f0 = wlds[wave][j];
            float2 f1 = wlds[wave][j + 4];
            float2 f2 = wlds[wave][j + 8];
            float2 f3 = wlds[wave][j + 12];
            float4 v0 = h4[(size_t)__float_as_int(f0.y) * 16 + c4];
            float4 v1 = h4[(size_t)__float_as_int(f1.y) * 16 + c4];
            float4 v2 = h4[(size_t)__float_as_int(f2.y) * 16 + c4];
            float4 v3 = h4[(size_t)__float_as_int(f3.y) * 16 + c4];
            acc.x = fmaf(f0.x, v0.x, acc.x);
            acc.y = fmaf(f0.x, v0.y, acc.y);
            acc.z = fmaf(f0.x, v0.z, acc.z);
            acc.w = fmaf(f0.x, v0.w, acc.w);
            acc.x = fmaf(f1.x, v1.x, acc.x);
            acc.y = fmaf(f1.x, v1.y, acc.y);
            acc.z = fmaf(f1.x, v1.z, acc.z);
            acc.w = fmaf(f1.x, v1.w, acc.w);
            acc.x = fmaf(f2.x, v2.x, acc.x);
            acc.y = fmaf(f2.x, v2.y, acc.y);
            acc.z = fmaf(f2.x, v2.z, acc.z);
            acc.w = fmaf(f2.x, v2.w, acc.w);
            acc.x = fmaf(f3.x, v3.x, acc.x);
            acc.y = fmaf(f3.x, v3.y, acc.y);
            acc.z = fmaf(f3.x, v3.z, acc.z);
            acc.w = fmaf(f3.x, v3.w, acc.w);
        }
        for (; j < deg; j += 4) {
            float2 f0 = wlds[wave][j];
            float4 v0 = h4[(size_t)__float_as_int(f0.y) * 16 + c4];
            acc.x = fmaf(f0.x, v0.x, acc.x);
            acc.y = fmaf(f0.x, v0.y, acc.y);
            acc.z = fmaf(f0.x, v0.z, acc.z);
            acc.w = fmaf(f0.x, v0.w, acc.w);
        }
    } else {
        float m = -1e30f;
        for (int i = b0 + gl; i < b1; i += 16) {
            int s = csr[i];
            float ev = alS[s] + adn;
            ev = ev > 0.f ? ev : 0.2f * ev;
            m = fmaxf(m, ev);
        }
        for (int d = 8; d; d >>= 1) m = fmaxf(m, __shfl_xor(m, d));
        float ssum = 0.f;
        for (int i = b0 + gl; i < b1; i += 16) {
            int s = csr[i];
            float ev = alS[s] + adn;
            ev = ev > 0.f ? ev : 0.2f * ev;
            float w = expf(ev - m);
            ssum += w;
        }
        for (int d = 8; d; d >>= 1) ssum += __shfl_xor(ssum, d);
        inv = 1.f / (ssum + 1e-16f);
        for (int i = b0 + grp; i < b1; i += 4) {
            int s = csr[i];
            float ev = alS[s] + adn;
            ev = ev > 0.f ? ev : 0.2f * ev;
            float w = expf(ev - m);
            float4 v = h4[(size_t)s * 16 + c4];
            acc.x = fmaf(w, v.x, acc.x);
            acc.y = fmaf(w, v.y, acc.y);
            acc.z = fmaf(w, v.z, acc.z);
            acc.w = fmaf(w, v.w, acc.w);
        }
    }
#pragma unroll
    for (int mask = 16; mask <= 32; mask <<= 1) {
        acc.x += __shfl_xor(acc.x, mask);
        acc.y += __shfl_xor(acc.y, mask);
        acc.z += __shfl_xor(acc.z, mask);
        acc.w += __shfl_xor(acc.w, mask);
    }
    if (grp == 0) {
        float4 b = ((const float4*)bias)[c4];
        float4 r;
        r.x = acc.x * inv + b.x;
        r.y = acc.y * inv + b.y;
        r.z = acc.z * inv + b.z;
        r.w = acc.w * inv + b.w;
        r.x = r.x > 0.f ? r.x : expm1f(r.x);
        r.y = r.y > 0.f ? r.y : expm1f(r.y);
        r.z = r.z > 0.f ? r.z : expm1f(r.z);
        r.w = r.w > 0.f ? r.w : expm1f(r.w);
        ((float4*)out)[(size_t)n * 16 + c4] = r;
    }
}

// ---------------- global mean pool (batch sorted) ----------------

__global__ __launch_bounds__(1024) void pool_k(const float* __restrict__ h,
                                               const int* __restrict__ batch,
                                               float* __restrict__ gout) {
    int g = blockIdx.x;
    __shared__ int sb, se;
    __shared__ float partial[16][64];
    int t = threadIdx.x, wave = t >> 6, c = t & 63;
    if (t == 0) {
        int lo = 0, hi = NN;
        while (lo < hi) { int mid = (lo + hi) >> 1; if (batch[mid] < g) lo = mid + 1; else hi = mid; }
        sb = lo;
        lo = 0; hi = NN;
        while (lo < hi) { int mid = (lo + hi) >> 1; if (batch[mid] < g + 1) lo = mid + 1; else hi = mid; }
        se = lo;
    }
    __syncthreads();
    float acc = 0.f;
    for (int r = sb + wave; r < se; r += 16) acc += h[(size_t)r * 64 + c];
    partial[wave][c] = acc;
    __syncthreads();
    if (wave == 0) {
        float s = 0.f;
#pragma unroll
        for (int wv = 0; wv < 16; wv++) s += partial[wv][c];
        int cnt = se - sb;
        gout[g * 64 + c] = s / fmaxf((float)cnt, 1.0f);
    }
}

// ---------------- MLP head ----------------

__global__ __launch_bounds__(64) void mlp_k(const float* __restrict__ g,
                                            const float* __restrict__ fw1,
                                            const float* __restrict__ fb1,
                                            const float* __restrict__ fw2,
                                            const float* __restrict__ fb2,
                                            float* __restrict__ out) {
    int gi = blockIdx.x;
    __shared__ float gv[64];
    __shared__ float hid[32];
    int t = threadIdx.x;
    gv[t] = g[gi * 64 + t];
    __syncthreads();
    if (t < 32) {
        float a = fb1[t];
        for (int c = 0; c < 64; c++) a += gv[c] * fw1[c * 32 + t];
        hid[t] = a > 0.f ? a : 0.f;
    }
    __syncthreads();
    if (t == 0) {
        float o = fb2[0];
        for (int j = 0; j < 32; j++) o += hid[j] * fw2[j];
        out[gi] = o;
    }
}

// ---------------- launch ----------------

extern "C" void kernel_launch(void* const* d_in, const int* in_sizes, int n_in,
                              void* d_out, int out_size, void* d_ws, size_t ws_size,
                              hipStream_t stream) {
    const float* x   = (const float*)d_in[0];
    const int*   ei  = (const int*)d_in[1];
    const int*   bat = (const int*)d_in[2];
    const float* w1  = (const float*)d_in[3];
    const float* as1 = (const float*)d_in[4];
    const float* ad1 = (const float*)d_in[5];
    const float* b1  = (const float*)d_in[6];
    const float* w2  = (const float*)d_in[7];
    const float* as2 = (const float*)d_in[8];
    const float* ad2 = (const float*)d_in[9];
    const float* b2  = (const float*)d_in[10];
    const float* w3  = (const float*)d_in[11];
    const float* as3 = (const float*)d_in[12];
    const float* ad3 = (const float*)d_in[13];
    const float* b3  = (const float*)d_in[14];
    const float* fw1 = (const float*)d_in[15];
    const float* fb1 = (const float*)d_in[16];
    const float* fw2 = (const float*)d_in[17];
    const float* fb2 = (const float*)d_in[18];
    float* out = (float*)d_out;

    char* ws = (char*)d_ws;
    size_t o = 0;
    auto alloc = [&](size_t bytes) -> void* {
        void* p = ws + o;
        o += (bytes + 255) & ~(size_t)255;
        return p;
    };
    int*    offsets = (int*)alloc((NN + 1) * sizeof(int));
    int*    ghist   = (int*)alloc(NHIST * sizeof(int));
    int*    gbase   = (int*)alloc(NHIST * sizeof(int));
    int*    bsum    = (int*)alloc(NSB * sizeof(int));
    int*    bpre    = (int*)alloc(NSB * sizeof(int));
    int*    packed  = (int*)alloc(ET * sizeof(int));
    int*    csr     = (int*)alloc(ET * sizeof(int));
    float*  l1out   = (float*)alloc((size_t)NN * 128 * sizeof(float));
    float*  hX      = (float*)alloc((size_t)NN * 64 * sizeof(float));
    float*  l2out   = (float*)alloc((size_t)NN * 64 * sizeof(float));
    float*  l3out   = (float*)alloc((size_t)NN * 64 * sizeof(float));
    float*  alS     = (float*)alloc((size_t)NN * 2 * sizeof(float));
    float*  alD     = (float*)alloc((size_t)NN * 2 * sizeof(float));
    float*  gbuf    = (float*)alloc((size_t)NG * 64 * sizeof(float));

    // CSR build: bucket partition (deterministic content; sortw canonicalizes order)
    hist_k<<<NCH, 256, 0, stream>>>(ei, ghist);
    gscan1_k<<<NSB, 256, 0, stream>>>(ghist, gbase, bsum, NHIST);
    gscan2_k<<<1, 256, 0, stream>>>(bsum, bpre, NSB, offsets + NN, ET);
    part_k<<<NCH, 256, 0, stream>>>(ei, gbase, bpre, packed);
    csr_k<<<NBUK, 256, 0, stream>>>(packed, gbase, bpre, csr, offsets);
    sortw_k<<<NN / 4, 256, 0, stream>>>(offsets, csr);

    // layer 1: alS/alD then fused alpha+agg, one wave per node, both heads
    feat1b_k<<<NN / 2, 256, 0, stream>>>(x, w1, as1, ad1, alS, alD);
    agg1_k<<<NN / 4, 256, 0, stream>>>((const float2*)x, w1, alS, alD, b1, offsets, csr, l1out);

    // layer 2: 128 -> 64
    gemm_al_k<128><<<NN / 16, 256, 0, stream>>>(l1out, w2, as2, ad2, hX, alS, alD);
    aggf2_k<<<NN / 4, 256, 0, stream>>>((const float4*)hX, alS, alD, b2, offsets, csr, l2out);

    // layer 3: 64 -> 64
    gemm_al_k<64><<<NN / 16, 256, 0, stream>>>(l2out, w3, as3, ad3, hX, alS, alD);
    aggf2_k<<<NN / 4, 256, 0, stream>>>((const float4*)hX, alS, alD, b3, offsets, csr, l3out);

    // pool + MLP head
    pool_k<<<NG, 1024, 0, stream>>>(l3out, bat, gbuf);
    mlp_k<<<NG, 64, 0, stream>>>(gbuf, fw1, fb1, fw2, fb2, out);
}

// Round 17
// 292.409 us; speedup vs baseline: 1.0591x; 1.0591x over previous
//
#include <hip/hip_runtime.h>
#include <hip/hip_bf16.h>
#include <math.h>

#define NN 50000
#define NE 800000
#define ET 850000      // NE + NN self loops
#define NG 64

// bucket partition geometry
#define NBUK 125
#define BS   400
#define CHK  8192
#define NCH  104
#define NHIST (NBUK * NCH)
#define NSB  ((NHIST + 255) / 256)

// ---------------- CSR build: bucket-partitioned ----------------

__global__ __launch_bounds__(256) void hist_k(const int* __restrict__ ei,
                                              int* __restrict__ ghist) {
    __shared__ int h[NBUK];
    int c = blockIdx.x, t = threadIdx.x;
    for (int i = t; i < NBUK; i += 256) h[i] = 0;
    __syncthreads();
    int e0 = c * CHK;
    int e1 = min(ET, e0 + CHK);
    for (int e = e0 + t; e < e1; e += 256) {
        int dst = (e < NE) ? ei[NE + e] : (e - NE);
        atomicAdd(&h[dst / BS], 1);
    }
    __syncthreads();
    for (int b = t; b < NBUK; b += 256) ghist[b * NCH + c] = h[b];
}

__global__ __launch_bounds__(256) void gscan1_k(const int* __restrict__ in,
                                                int* __restrict__ out,
                                                int* __restrict__ bsum, int n) {
    int t = threadIdx.x;
    int idx = blockIdx.x * 256 + t;
    int v = (idx < n) ? in[idx] : 0;
    int lane = t & 63, wave = t >> 6;
    int inc = v;
#pragma unroll
    for (int d = 1; d < 64; d <<= 1) {
        int u = __shfl_up(inc, d);
        if (lane >= d) inc += u;
    }
    __shared__ int wtot[4];
    if (lane == 63) wtot[wave] = inc;
    __syncthreads();
    int wpre = 0;
    for (int w = 0; w < wave; w++) wpre += wtot[w];
    if (idx < n) out[idx] = wpre + inc - v;
    if (t == 255) bsum[blockIdx.x] = wpre + inc;
}

__global__ __launch_bounds__(256) void gscan2_k(const int* __restrict__ bsum,
                                                int* __restrict__ bpre, int nb,
                                                int* __restrict__ tailp, int tailv) {
    int t = threadIdx.x;
    int v = (t < nb) ? bsum[t] : 0;
    int lane = t & 63, wave = t >> 6;
    int inc = v;
#pragma unroll
    for (int d = 1; d < 64; d <<= 1) {
        int u = __shfl_up(inc, d);
        if (lane >= d) inc += u;
    }
    __shared__ int wtot[4];
    if (lane == 63) wtot[wave] = inc;
    __syncthreads();
    int wpre = 0;
    for (int w = 0; w < wave; w++) wpre += wtot[w];
    if (t < nb) bpre[t] = wpre + inc - v;
    if (t == 0 && tailp) *tailp = tailv;
}

__global__ __launch_bounds__(256) void part_k(const int* __restrict__ ei,
                                              const int* __restrict__ gbase,
                                              const int* __restrict__ bpre,
                                              int* __restrict__ packed) {
    __shared__ int cur[NBUK];
    __shared__ int baseL[NBUK];
    int c = blockIdx.x, t = threadIdx.x;
    for (int i = t; i < NBUK; i += 256) {
        int idx = i * NCH + c;
        cur[i] = 0;
        baseL[i] = gbase[idx] + bpre[idx >> 8];
    }
    __syncthreads();
    int e0 = c * CHK;
    int e1 = min(ET, e0 + CHK);
    for (int e = e0 + t; e < e1; e += 256) {
        int src, dst;
        if (e < NE) { src = ei[e]; dst = ei[NE + e]; }
        else        { src = dst = e - NE; }
        int b = dst / BS;
        int r = atomicAdd(&cur[b], 1);
        packed[baseL[b] + r] = ((dst - b * BS) << 17) | src;
    }
}

__global__ __launch_bounds__(256) void csr_k(const int* __restrict__ packed,
                                             const int* __restrict__ gbase,
                                             const int* __restrict__ bpre,
                                             int* __restrict__ csr,
                                             int* __restrict__ offsets) {
    __shared__ int cnt[BS];
    __shared__ int sc[2][512];
    __shared__ int cur[BS];
    __shared__ int Ss, Ts;
    int b = blockIdx.x, t = threadIdx.x;
    for (int i = t; i < BS; i += 256) cnt[i] = 0;
    if (t == 0) {
        int i0 = b * NCH;
        Ss = gbase[i0] + bpre[i0 >> 8];
        int i1 = (b + 1) * NCH;
        Ts = (b == NBUK - 1) ? ET : (gbase[i1] + bpre[i1 >> 8]);
    }
    __syncthreads();
    int n0 = Ss, n1 = Ts;
    for (int i = n0 + t; i < n1; i += 256) {
        int p = packed[i];
        atomicAdd(&cnt[p >> 17], 1);
    }
    __syncthreads();
    for (int i = t; i < 512; i += 256) sc[0][i] = (i < BS) ? cnt[i] : 0;
    __syncthreads();
    int pp = 0;
    for (int d = 1; d < 512; d <<= 1) {
        for (int i = t; i < 512; i += 256) {
            int v = sc[pp][i];
            if (i >= d) v += sc[pp][i - d];
            sc[pp ^ 1][i] = v;
        }
        pp ^= 1;
        __syncthreads();
    }
    for (int i = t; i < BS; i += 256) {
        int pre = (i == 0) ? 0 : sc[pp][i - 1];
        offsets[b * BS + i] = Ss + pre;
        cur[i] = Ss + pre;
    }
    __syncthreads();
    for (int i = n0 + t; i < n1; i += 256) {
        int p = packed[i];
        int pos = atomicAdd(&cur[p >> 17], 1);
        csr[pos] = p & 0x1FFFF;
    }
}

__global__ __launch_bounds__(256) void sortw_k(const int* __restrict__ offsets,
                                               int* __restrict__ csr) {
    int gt = blockIdx.x * blockDim.x + threadIdx.x;
    int n = gt >> 6;
    int lane = gt & 63;
    if (n >= NN) return;
    int b0 = offsets[n], b1 = offsets[n + 1];
    int deg = b1 - b0;
    if (deg <= 1) return;
    if (deg <= 64) {
        int v = (lane < deg) ? csr[b0 + lane] : 0x7FFFFFFF;
#pragma unroll
        for (int k = 2; k <= 64; k <<= 1) {
#pragma unroll
            for (int j = k >> 1; j > 0; j >>= 1) {
                int partner = __shfl_xor(v, j);
                bool up = ((lane & k) == 0);
                bool keepmin = (((lane & j) == 0) == up);
                v = keepmin ? min(v, partner) : max(v, partner);
            }
        }
        if (lane < deg) csr[b0 + lane] = v;
    } else if (lane == 0) {
        for (int i = b0 + 1; i < b1; i++) {
            int v = csr[i];
            int j = i - 1;
            while (j >= b0 && csr[j] > v) { csr[j + 1] = csr[j]; j--; }
            csr[j + 1] = v;
        }
    }
}

// ---------------- layer-1 alS/alD ----------------

__global__ __launch_bounds__(256) void feat1b_k(const float* __restrict__ x,
                                                const float* __restrict__ w1,
                                                const float* __restrict__ as1,
                                                const float* __restrict__ ad1,
                                                float* __restrict__ alS,
                                                float* __restrict__ alD) {
    int t = threadIdx.x;
    int tt = t & 127;
    int n = blockIdx.x * 2 + (t >> 7);
    float x0 = x[n * 2 + 0], x1 = x[n * 2 + 1];
    float v = x0 * w1[tt] + x1 * w1[128 + tt];
    int head = (t >> 6) & 1, lane = t & 63;
    float ps = v * as1[tt];
    float pd = v * ad1[tt];
    for (int d = 32; d; d >>= 1) {
        ps += __shfl_down(ps, d);
        pd += __shfl_down(pd, d);
    }
    if (lane == 0) {
        alS[n * 2 + head] = ps;
        alD[n * 2 + head] = pd;
    }
}

// ---------------- fused layer 1: ONE wave per node, both heads (best-measured r12 config) ----------------

__global__ __launch_bounds__(256) void agg1_k(const float2* __restrict__ x2,
                                              const float* __restrict__ w1,
                                              const float* __restrict__ alS,
                                              const float* __restrict__ alD,
                                              const float* __restrict__ bias,
                                              const int* __restrict__ offsets,
                                              const int* __restrict__ csr,
                                              float* __restrict__ out) {
    __shared__ float4 wslds[4][64];
    int t = threadIdx.x;
    int wave = t >> 6, lane = t & 63, grp = lane >> 4, c4 = lane & 15;
    int gl = lane & 15;
    int n = blockIdx.x * 4 + wave;
    int b0 = offsets[n], b1 = offsets[n + 1];
    int deg = b1 - b0;
    float2 adv = ((const float2*)alD)[n];
    const float2* alS2 = (const float2*)alS;

    float4 wa0 = ((const float4*)w1)[c4];
    float4 wa1 = ((const float4*)w1)[16 + c4];
    float4 wb0 = ((const float4*)(w1 + 128))[c4];
    float4 wb1 = ((const float4*)(w1 + 128))[16 + c4];
    float4 acc0 = make_float4(0.f, 0.f, 0.f, 0.f);
    float4 acc1 = make_float4(0.f, 0.f, 0.f, 0.f);
    float inv0, inv1;

    if (deg <= 64) {
        bool valid = lane < deg;
        int s = 0; float ev0 = -1e30f, ev1 = -1e30f;
        if (valid) {
            s = csr[b0 + lane];
            float2 al = alS2[s];
            float e0 = al.x + adv.x;
            ev0 = e0 > 0.f ? e0 : 0.2f * e0;
            float e1 = al.y + adv.y;
            ev1 = e1 > 0.f ? e1 : 0.2f * e1;
        }
        float m0 = ev0, m1 = ev1;
#pragma unroll
        for (int d = 32; d; d >>= 1) {
            m0 = fmaxf(m0, __shfl_xor(m0, d));
            m1 = fmaxf(m1, __shfl_xor(m1, d));
        }
        if (valid) {
            float w0 = expf(ev0 - m0);
            float w1v = expf(ev1 - m1);
            wslds[wave][lane] = make_float4(w0, w1v, __int_as_float(s), 0.f);
        }
        float ssum0 = 0.f, ssum1 = 0.f;
#pragma unroll
        for (int k = 0; k < 4; k++) {
            int j = gl + 16 * k;
            if (j < deg) {
                float4 f = wslds[wave][j];
                ssum0 += f.x;
                ssum1 += f.y;
            }
        }
        for (int d = 8; d; d >>= 1) {
            ssum0 += __shfl_xor(ssum0, d);
            ssum1 += __shfl_xor(ssum1, d);
        }
        inv0 = 1.f / (ssum0 + 1e-16f);
        inv1 = 1.f / (ssum1 + 1e-16f);
        int j = grp;
        for (; j + 4 < deg; j += 8) {
            float4 fa = wslds[wave][j];
            float4 fb = wslds[wave][j + 4];
            float2 xa = x2[__float_as_int(fa.z)];
            float2 xb = x2[__float_as_int(fb.z)];
            float4 v0, v1;
            v0.x = xa.x * wa0.x + xa.y * wb0.x;
            v0.y = xa.x * wa0.y + xa.y * wb0.y;
            v0.z = xa.x * wa0.z + xa.y * wb0.z;
            v0.w = xa.x * wa0.w + xa.y * wb0.w;
            v1.x = xa.x * wa1.x + xa.y * wb1.x;
            v1.y = xa.x * wa1.y + xa.y * wb1.y;
            v1.z = xa.x * wa1.z + xa.y * wb1.z;
            v1.w = xa.x * wa1.w + xa.y * wb1.w;
            acc0.x = fmaf(fa.x, v0.x, acc0.x);
            acc0.y = fmaf(fa.x, v0.y, acc0.y);
            acc0.z = fmaf(fa.x, v0.z, acc0.z);
            acc0.w = fmaf(fa.x, v0.w, acc0.w);
            acc1.x = fmaf(fa.y, v1.x, acc1.x);
            acc1.y = fmaf(fa.y, v1.y, acc1.y);
            acc1.z = fmaf(fa.y, v1.z, acc1.z);
            acc1.w = fmaf(fa.y, v1.w, acc1.w);
            v0.x = xb.x * wa0.x + xb.y * wb0.x;
            v0.y = xb.x * wa0.y + xb.y * wb0.y;
            v0.z = xb.x * wa0.z + xb.y * wb0.z;
            v0.w = xb.x * wa0.w + xb.y * wb0.w;
            v1.x = xb.x * wa1.x + xb.y * wb1.x;
            v1.y = xb.x * wa1.y + xb.y * wb1.y;
            v1.z = xb.x * wa1.z + xb.y * wb1.z;
            v1.w = xb.x * wa1.w + xb.y * wb1.w;
            acc0.x = fmaf(fb.x, v0.x, acc0.x);
            acc0.y = fmaf(fb.x, v0.y, acc0.y);
            acc0.z = fmaf(fb.x, v0.z, acc0.z);
            acc0.w = fmaf(fb.x, v0.w, acc0.w);
            acc1.x = fmaf(fb.y, v1.x, acc1.x);
            acc1.y = fmaf(fb.y, v1.y, acc1.y);
            acc1.z = fmaf(fb.y, v1.z, acc1.z);
            acc1.w = fmaf(fb.y, v1.w, acc1.w);
        }
        if (j < deg) {
            float4 fa = wslds[wave][j];
            float2 xa = x2[__float_as_int(fa.z)];
            float4 v0, v1;
            v0.x = xa.x * wa0.x + xa.y * wb0.x;
            v0.y = xa.x * wa0.y + xa.y * wb0.y;
            v0.z = xa.x * wa0.z + xa.y * wb0.z;
            v0.w = xa.x * wa0.w + xa.y * wb0.w;
            v1.x = xa.x * wa1.x + xa.y * wb1.x;
            v1.y = xa.x * wa1.y + xa.y * wb1.y;
            v1.z = xa.x * wa1.z + xa.y * wb1.z;
            v1.w = xa.x * wa1.w + xa.y * wb1.w;
            acc0.x = fmaf(fa.x, v0.x, acc0.x);
            acc0.y = fmaf(fa.x, v0.y, acc0.y);
            acc0.z = fmaf(fa.x, v0.z, acc0.z);
            acc0.w = fmaf(fa.x, v0.w, acc0.w);
            acc1.x = fmaf(fa.y, v1.x, acc1.x);
            acc1.y = fmaf(fa.y, v1.y, acc1.y);
            acc1.z = fmaf(fa.y, v1.z, acc1.z);
            acc1.w = fmaf(fa.y, v1.w, acc1.w);
        }
    } else {
        for (int head = 0; head < 2; head++) {
            float ad = head ? adv.y : adv.x;
            float4 wa = head ? wa1 : wa0, wb = head ? wb1 : wb0;
            float m = -1e30f;
            for (int i = b0 + gl; i < b1; i += 16) {
                int s = csr[i];
                float ev = alS[s * 2 + head] + ad;
                ev = ev > 0.f ? ev : 0.2f * ev;
                m = fmaxf(m, ev);
            }
            for (int d = 8; d; d >>= 1) m = fmaxf(m, __shfl_xor(m, d));
            float ssum = 0.f;
            for (int i = b0 + gl; i < b1; i += 16) {
                int s = csr[i];
                float ev = alS[s * 2 + head] + ad;
                ev = ev > 0.f ? ev : 0.2f * ev;
                float w = expf(ev - m);
                ssum += w;
            }
            for (int d = 8; d; d >>= 1) ssum += __shfl_xor(ssum, d);
            float invh = 1.f / (ssum + 1e-16f);
            float4 acc = make_float4(0.f, 0.f, 0.f, 0.f);
            for (int i = b0 + grp; i < b1; i += 4) {
                int s = csr[i];
                float ev = alS[s * 2 + head] + ad;
                ev = ev > 0.f ? ev : 0.2f * ev;
                float w = expf(ev - m);
                float2 xs = x2[s];
                float4 v;
                v.x = xs.x * wa.x + xs.y * wb.x;
                v.y = xs.x * wa.y + xs.y * wb.y;
                v.z = xs.x * wa.z + xs.y * wb.z;
                v.w = xs.x * wa.w + xs.y * wb.w;
                acc.x = fmaf(w, v.x, acc.x);
                acc.y = fmaf(w, v.y, acc.y);
                acc.z = fmaf(w, v.z, acc.z);
                acc.w = fmaf(w, v.w, acc.w);
            }
            if (head == 0) { acc0 = acc; inv0 = invh; }
            else           { acc1 = acc; inv1 = invh; }
        }
    }
#pragma unroll
    for (int mask = 16; mask <= 32; mask <<= 1) {
        acc0.x += __shfl_xor(acc0.x, mask);
        acc0.y += __shfl_xor(acc0.y, mask);
        acc0.z += __shfl_xor(acc0.z, mask);
        acc0.w += __shfl_xor(acc0.w, mask);
        acc1.x += __shfl_xor(acc1.x, mask);
        acc1.y += __shfl_xor(acc1.y, mask);
        acc1.z += __shfl_xor(acc1.z, mask);
        acc1.w += __shfl_xor(acc1.w, mask);
    }
    if (grp < 2) {
        float4 acc = (grp == 0) ? acc0 : acc1;
        float inv = (grp == 0) ? inv0 : inv1;
        float4 b = ((const float4*)bias)[grp * 16 + c4];
        float4 r;
        r.x = acc.x * inv + b.x;
        r.y = acc.y * inv + b.y;
        r.z = acc.z * inv + b.z;
        r.w = acc.w * inv + b.w;
        r.x = r.x > 0.f ? r.x : expm1f(r.x);
        r.y = r.y > 0.f ? r.y : expm1f(r.y);
        r.z = r.z > 0.f ? r.z : expm1f(r.z);
        r.w = r.w > 0.f ? r.w : expm1f(r.w);
        ((float4*)out)[((size_t)n * 2 + grp) * 16 + c4] = r;
    }
}

// ---------------- GEMM + al for layers 2/3: 4 nodes/wave + float4 rowb reads ----------------
// FMA chain per output stays k-ascending (rv.x..rv.w in order) -> bit-identical.

template <int K>
__global__ __launch_bounds__(256) void gemm_al_k(const float* __restrict__ in,
                                                 const float* __restrict__ W,
                                                 const float* __restrict__ as,
                                                 const float* __restrict__ ad,
                                                 float* __restrict__ h,
                                                 float* __restrict__ alS,
                                                 float* __restrict__ alD) {
    __shared__ float Wl[K * 64];
    __shared__ float rowb[16][K];
    int t = threadIdx.x;
    for (int i = t; i < K * 64; i += 256) Wl[i] = W[i];
    int wave = t >> 6, c = t & 63;
    int nb = blockIdx.x * 16 + wave * 4;
#pragma unroll
    for (int r = 0; r < 4; r++) {
        const float* row = in + (size_t)(nb + r) * K;
        for (int k = c; k < K; k += 64) rowb[wave * 4 + r][k] = row[k];
    }
    __syncthreads();
    const float* rb0 = rowb[wave * 4 + 0];
    const float* rb1 = rowb[wave * 4 + 1];
    const float* rb2 = rowb[wave * 4 + 2];
    const float* rb3 = rowb[wave * 4 + 3];
    float a0 = 0.f, a1 = 0.f, a2 = 0.f, a3 = 0.f;
#pragma unroll
    for (int k = 0; k < K; k += 4) {
        float4 rv0 = *(const float4*)&rb0[k];
        float4 rv1 = *(const float4*)&rb1[k];
        float4 rv2 = *(const float4*)&rb2[k];
        float4 rv3 = *(const float4*)&rb3[k];
        float wv0 = Wl[(k + 0) * 64 + c];
        float wv1 = Wl[(k + 1) * 64 + c];
        float wv2 = Wl[(k + 2) * 64 + c];
        float wv3 = Wl[(k + 3) * 64 + c];
        a0 = fmaf(rv0.x, wv0, a0); a0 = fmaf(rv0.y, wv1, a0);
        a0 = fmaf(rv0.z, wv2, a0); a0 = fmaf(rv0.w, wv3, a0);
        a1 = fmaf(rv1.x, wv0, a1); a1 = fmaf(rv1.y, wv1, a1);
        a1 = fmaf(rv1.z, wv2, a1); a1 = fmaf(rv1.w, wv3, a1);
        a2 = fmaf(rv2.x, wv0, a2); a2 = fmaf(rv2.y, wv1, a2);
        a2 = fmaf(rv2.z, wv2, a2); a2 = fmaf(rv2.w, wv3, a2);
        a3 = fmaf(rv3.x, wv0, a3); a3 = fmaf(rv3.y, wv1, a3);
        a3 = fmaf(rv3.z, wv2, a3); a3 = fmaf(rv3.w, wv3, a3);
    }
    h[(size_t)(nb + 0) * 64 + c] = a0;
    h[(size_t)(nb + 1) * 64 + c] = a1;
    h[(size_t)(nb + 2) * 64 + c] = a2;
    h[(size_t)(nb + 3) * 64 + c] = a3;
    float asc = as[c], adc = ad[c];
    float ps0 = a0 * asc, pd0 = a0 * adc;
    float ps1 = a1 * asc, pd1 = a1 * adc;
    float ps2 = a2 * asc, pd2 = a2 * adc;
    float ps3 = a3 * asc, pd3 = a3 * adc;
    for (int d = 32; d; d >>= 1) {
        ps0 += __shfl_down(ps0, d); pd0 += __shfl_down(pd0, d);
        ps1 += __shfl_down(ps1, d); pd1 += __shfl_down(pd1, d);
        ps2 += __shfl_down(ps2, d); pd2 += __shfl_down(pd2, d);
        ps3 += __shfl_down(ps3, d); pd3 += __shfl_down(pd3, d);
    }
    if (c == 0) {
        alS[nb + 0] = ps0; alD[nb + 0] = pd0;
        alS[nb + 1] = ps1; alD[nb + 1] = pd1;
        alS[nb + 2] = ps2; alD[nb + 2] = pd2;
        alS[nb + 3] = ps3; alD[nb + 3] = pd3;
    }
}

// ---------------- fused layers 2/3: 64-lane alpha + unroll-4 h4 gather agg ----------------

__global__ __launch_bounds__(256) void aggf2_k(const float4* __restrict__ h4,
                                               const float* __restrict__ alS,
                                               const float* __restrict__ alD,
                                               const float* __restrict__ bias,
                                               const int* __restrict__ offsets,
                                               const int* __restrict__ csr,
                                               float* __restrict__ out) {
    __shared__ float2 wlds[4][64];          // {w, s_bits}
    int t = threadIdx.x;
    int wave = t >> 6, lane = t & 63, grp = lane >> 4, c4 = lane & 15;
    int gl = lane & 15;
    int n = blockIdx.x * 4 + wave;
    int b0 = offsets[n], b1 = offsets[n + 1];
    int deg = b1 - b0;
    float adn = alD[n];

    float4 acc = make_float4(0.f, 0.f, 0.f, 0.f);
    float inv;

    if (deg <= 64) {
        bool valid = lane < deg;
        int s = 0; float ev = -1e30f;
        if (valid) {
            s = csr[b0 + lane];
            float e0 = alS[s] + adn;
            ev = e0 > 0.f ? e0 : 0.2f * e0;
        }
        float m = ev;
#pragma unroll
        for (int d = 32; d; d >>= 1) m = fmaxf(m, __shfl_xor(m, d));
        if (valid) {
            float w = expf(ev - m);
            wlds[wave][lane] = make_float2(w, __int_as_float(s));
        }
        float ssum = 0.f;
#pragma unroll
        for (int k = 0; k < 4; k++) {
            int j = gl + 16 * k;
            if (j < deg) ssum += wlds[wave][j].x;
        }
        for (int d = 8; d; d >>= 1) ssum += __shfl_xor(ssum, d);
        inv = 1.f / (ssum + 1e-16f);
        int j = grp;
        for (; j + 12 < deg; j += 16) {
            float2 f0 = wlds[wave][j];
            float2 f1 = wlds[wave][j + 4];
            float2 f2 = wlds[wave][j + 8];
            float2 f3 = wlds[wave][j + 12];
            float4 v0 = h4[(size_t)__float_as_int(f0.y) * 16 + c4];
            float4 v1 = h4[(size_t)__float_as_int(f1.y) * 16 + c4];
            float4 v2 = h4[(size_t)__float_as_int(f2.y) * 16 + c4];
            float4 v3 = h4[(size_t)__float_as_int(f3.y) * 16 + c4];
            acc.x = fmaf(f0.x, v0.x, acc.x);
            acc.y = fmaf(f0.x, v0.y, acc.y);
            acc.z = fmaf(f0.x, v0.z, acc.z);
            acc.w = fmaf(f0.x, v0.w, acc.w);
            acc.x = fmaf(f1.x, v1.x, acc.x);
            acc.y = fmaf(f1.x, v1.y, acc.y);
            acc.z = fmaf(f1.x, v1.z, acc.z);
            acc.w = fmaf(f1.x, v1.w, acc.w);
            acc.x = fmaf(f2.x, v2.x, acc.x);
            acc.y = fmaf(f2.x, v2.y, acc.y);
            acc.z = fmaf(f2.x, v2.z, acc.z);
            acc.w = fmaf(f2.x, v2.w, acc.w);
            acc.x = fmaf(f3.x, v3.x, acc.x);
            acc.y = fmaf(f3.x, v3.y, acc.y);
            acc.z = fmaf(f3.x, v3.z, acc.z);
            acc.w = fmaf(f3.x, v3.w, acc.w);
        }
        for (; j < deg; j += 4) {
            float2 f0 = wlds[wave][j];
            float4 v0 = h4[(size_t)__float_as_int(f0.y) * 16 + c4];
            acc.x = fmaf(f0.x, v0.x, acc.x);
            acc.y = fmaf(f0.x, v0.y, acc.y);
            acc.z = fmaf(f0.x, v0.z, acc.z);
            acc.w = fmaf(f0.x, v0.w, acc.w);
        }
    } else {
        float m = -1e30f;
        for (int i = b0 + gl; i < b1; i += 16) {
            int s = csr[i];
            float ev = alS[s] + adn;
            ev = ev > 0.f ? ev : 0.2f * ev;
            m = fmaxf(m, ev);
        }
        for (int d = 8; d; d >>= 1) m = fmaxf(m, __shfl_xor(m, d));
        float ssum = 0.f;
        for (int i = b0 + gl; i < b1; i += 16) {
            int s = csr[i];
            float ev = alS[s] + adn;
            ev = ev > 0.f ? ev : 0.2f * ev;
            float w = expf(ev - m);
            ssum += w;
        }
        for (int d = 8; d; d >>= 1) ssum += __shfl_xor(ssum, d);
        inv = 1.f / (ssum + 1e-16f);
        for (int i = b0 + grp; i < b1; i += 4) {
            int s = csr[i];
            float ev = alS[s] + adn;
            ev = ev > 0.f ? ev : 0.2f * ev;
            float w = expf(ev - m);
            float4 v = h4[(size_t)s * 16 + c4];
            acc.x = fmaf(w, v.x, acc.x);
            acc.y = fmaf(w, v.y, acc.y);
            acc.z = fmaf(w, v.z, acc.z);
            acc.w = fmaf(w, v.w, acc.w);
        }
    }
#pragma unroll
    for (int mask = 16; mask <= 32; mask <<= 1) {
        acc.x += __shfl_xor(acc.x, mask);
        acc.y += __shfl_xor(acc.y, mask);
        acc.z += __shfl_xor(acc.z, mask);
        acc.w += __shfl_xor(acc.w, mask);
    }
    if (grp == 0) {
        float4 b = ((const float4*)bias)[c4];
        float4 r;
        r.x = acc.x * inv + b.x;
        r.y = acc.y * inv + b.y;
        r.z = acc.z * inv + b.z;
        r.w = acc.w * inv + b.w;
        r.x = r.x > 0.f ? r.x : expm1f(r.x);
        r.y = r.y > 0.f ? r.y : expm1f(r.y);
        r.z = r.z > 0.f ? r.z : expm1f(r.z);
        r.w = r.w > 0.f ? r.w : expm1f(r.w);
        ((float4*)out)[(size_t)n * 16 + c4] = r;
    }
}

// ---------------- global mean pool (batch sorted) ----------------

__global__ __launch_bounds__(1024) void pool_k(const float* __restrict__ h,
                                               const int* __restrict__ batch,
                                               float* __restrict__ gout) {
    int g = blockIdx.x;
    __shared__ int sb, se;
    __shared__ float partial[16][64];
    int t = threadIdx.x, wave = t >> 6, c = t & 63;
    if (t == 0) {
        int lo = 0, hi = NN;
        while (lo < hi) { int mid = (lo + hi) >> 1; if (batch[mid] < g) lo = mid + 1; else hi = mid; }
        sb = lo;
        lo = 0; hi = NN;
        while (lo < hi) { int mid = (lo + hi) >> 1; if (batch[mid] < g + 1) lo = mid + 1; else hi = mid; }
        se = lo;
    }
    __syncthreads();
    float acc = 0.f;
    for (int r = sb + wave; r < se; r += 16) acc += h[(size_t)r * 64 + c];
    partial[wave][c] = acc;
    __syncthreads();
    if (wave == 0) {
        float s = 0.f;
#pragma unroll
        for (int wv = 0; wv < 16; wv++) s += partial[wv][c];
        int cnt = se - sb;
        gout[g * 64 + c] = s / fmaxf((float)cnt, 1.0f);
    }
}

// ---------------- MLP head ----------------

__global__ __launch_bounds__(64) void mlp_k(const float* __restrict__ g,
                                            const float* __restrict__ fw1,
                                            const float* __restrict__ fb1,
                                            const float* __restrict__ fw2,
                                            const float* __restrict__ fb2,
                                            float* __restrict__ out) {
    int gi = blockIdx.x;
    __shared__ float gv[64];
    __shared__ float hid[32];
    int t = threadIdx.x;
    gv[t] = g[gi * 64 + t];
    __syncthreads();
    if (t < 32) {
        float a = fb1[t];
        for (int c = 0; c < 64; c++) a += gv[c] * fw1[c * 32 + t];
        hid[t] = a > 0.f ? a : 0.f;
    }
    __syncthreads();
    if (t == 0) {
        float o = fb2[0];
        for (int j = 0; j < 32; j++) o += hid[j] * fw2[j];
        out[gi] = o;
    }
}

// ---------------- launch ----------------

extern "C" void kernel_launch(void* const* d_in, const int* in_sizes, int n_in,
                              void* d_out, int out_size, void* d_ws, size_t ws_size,
                              hipStream_t stream) {
    const float* x   = (const float*)d_in[0];
    const int*   ei  = (const int*)d_in[1];
    const int*   bat = (const int*)d_in[2];
    const float* w1  = (const float*)d_in[3];
    const float* as1 = (const float*)d_in[4];
    const float* ad1 = (const float*)d_in[5];
    const float* b1  = (const float*)d_in[6];
    const float* w2  = (const float*)d_in[7];
    const float* as2 = (const float*)d_in[8];
    const float* ad2 = (const float*)d_in[9];
    const float* b2  = (const float*)d_in[10];
    const float* w3  = (const float*)d_in[11];
    const float* as3 = (const float*)d_in[12];
    const float* ad3 = (const float*)d_in[13];
    const float* b3  = (const float*)d_in[14];
    const float* fw1 = (const float*)d_in[15];
    const float* fb1 = (const float*)d_in[16];
    const float* fw2 = (const float*)d_in[17];
    const float* fb2 = (const float*)d_in[18];
    float* out = (float*)d_out;

    char* ws = (char*)d_ws;
    size_t o = 0;
    auto alloc = [&](size_t bytes) -> void* {
        void* p = ws + o;
        o += (bytes + 255) & ~(size_t)255;
        return p;
    };
    int*    offsets = (int*)alloc((NN + 1) * sizeof(int));
    int*    ghist   = (int*)alloc(NHIST * sizeof(int));
    int*    gbase   = (int*)alloc(NHIST * sizeof(int));
    int*    bsum    = (int*)alloc(NSB * sizeof(int));
    int*    bpre    = (int*)alloc(NSB * sizeof(int));
    int*    packed  = (int*)alloc(ET * sizeof(int));
    int*    csr     = (int*)alloc(ET * sizeof(int));
    float*  l1out   = (float*)alloc((size_t)NN * 128 * sizeof(float));
    float*  hX      = (float*)alloc((size_t)NN * 64 * sizeof(float));
    float*  l2out   = (float*)alloc((size_t)NN * 64 * sizeof(float));
    float*  l3out   = (float*)alloc((size_t)NN * 64 * sizeof(float));
    float*  alS     = (float*)alloc((size_t)NN * 2 * sizeof(float));
    float*  alD     = (float*)alloc((size_t)NN * 2 * sizeof(float));
    float*  gbuf    = (float*)alloc((size_t)NG * 64 * sizeof(float));

    // CSR build: bucket partition (deterministic content; sortw canonicalizes order)
    hist_k<<<NCH, 256, 0, stream>>>(ei, ghist);
    gscan1_k<<<NSB, 256, 0, stream>>>(ghist, gbase, bsum, NHIST);
    gscan2_k<<<1, 256, 0, stream>>>(bsum, bpre, NSB, offsets + NN, ET);
    part_k<<<NCH, 256, 0, stream>>>(ei, gbase, bpre, packed);
    csr_k<<<NBUK, 256, 0, stream>>>(packed, gbase, bpre, csr, offsets);
    sortw_k<<<NN / 4, 256, 0, stream>>>(offsets, csr);

    // layer 1: alS/alD then fused alpha+agg, one wave per node, both heads
    feat1b_k<<<NN / 2, 256, 0, stream>>>(x, w1, as1, ad1, alS, alD);
    agg1_k<<<NN / 4, 256, 0, stream>>>((const float2*)x, w1, alS, alD, b1, offsets, csr, l1out);

    // layer 2: 128 -> 64
    gemm_al_k<128><<<NN / 16, 256, 0, stream>>>(l1out, w2, as2, ad2, hX, alS, alD);
    aggf2_k<<<NN / 4, 256, 0, stream>>>((const float4*)hX, alS, alD, b2, offsets, csr, l2out);

    // layer 3: 64 -> 64
    gemm_al_k<64><<<NN / 16, 256, 0, stream>>>(l2out, w3, as3, ad3, hX, alS, alD);
    aggf2_k<<<NN / 4, 256, 0, stream>>>((const float4*)hX, alS, alD, b3, offsets, csr, l3out);

    // pool + MLP head
    pool_k<<<NG, 1024, 0, stream>>>(l3out, bat, gbuf);
    mlp_k<<<NG, 64, 0, stream>>>(gbuf, fw1, fb1, fw2, fb2, out);
}

// Round 18
// 280.190 us; speedup vs baseline: 1.1053x; 1.0436x over previous
//
#include <hip/hip_runtime.h>
#include <hip/hip_bf16.h>
#include <math.h>

#define NN 50000
#define NE 800000
#define ET 850000      // NE + NN self loops
#define NG 64

// bucket partition geometry
#define NBUK 125       // buckets
#define BS   400       // nodes per bucket (125*400 = 50000)
#define CHK  8192      // edges per chunk
#define NCH  104       // ceil(ET/CHK)
#define NHIST (NBUK * NCH)          // 13000
#define NSB  ((NHIST + 255) / 256)  // 51 scan blocks

// ---------------- CSR build: bucket-partitioned (kills write amplification) ----------------

__global__ __launch_bounds__(256) void hist_k(const int* __restrict__ ei,
                                              int* __restrict__ ghist) {
    __shared__ int h[NBUK];
    int c = blockIdx.x, t = threadIdx.x;
    for (int i = t; i < NBUK; i += 256) h[i] = 0;
    __syncthreads();
    int e0 = c * CHK;
    int e1 = min(ET, e0 + CHK);
    for (int e = e0 + t; e < e1; e += 256) {
        int dst = (e < NE) ? ei[NE + e] : (e - NE);
        atomicAdd(&h[dst / BS], 1);
    }
    __syncthreads();
    for (int b = t; b < NBUK; b += 256) ghist[b * NCH + c] = h[b];
}

// generic hierarchical exclusive scan (n elements)
__global__ __launch_bounds__(256) void gscan1_k(const int* __restrict__ in,
                                                int* __restrict__ out,
                                                int* __restrict__ bsum, int n) {
    int t = threadIdx.x;
    int idx = blockIdx.x * 256 + t;
    int v = (idx < n) ? in[idx] : 0;
    int lane = t & 63, wave = t >> 6;
    int inc = v;
#pragma unroll
    for (int d = 1; d < 64; d <<= 1) {
        int u = __shfl_up(inc, d);
        if (lane >= d) inc += u;
    }
    __shared__ int wtot[4];
    if (lane == 63) wtot[wave] = inc;
    __syncthreads();
    int wpre = 0;
    for (int w = 0; w < wave; w++) wpre += wtot[w];
    if (idx < n) out[idx] = wpre + inc - v;
    if (t == 255) bsum[blockIdx.x] = wpre + inc;
}

__global__ __launch_bounds__(256) void gscan2_k(const int* __restrict__ bsum,
                                                int* __restrict__ bpre, int nb,
                                                int* __restrict__ tailp, int tailv) {
    int t = threadIdx.x;
    int v = (t < nb) ? bsum[t] : 0;
    int lane = t & 63, wave = t >> 6;
    int inc = v;
#pragma unroll
    for (int d = 1; d < 64; d <<= 1) {
        int u = __shfl_up(inc, d);
        if (lane >= d) inc += u;
    }
    __shared__ int wtot[4];
    if (lane == 63) wtot[wave] = inc;
    __syncthreads();
    int wpre = 0;
    for (int w = 0; w < wave; w++) wpre += wtot[w];
    if (t < nb) bpre[t] = wpre + inc - v;
    if (t == 0 && tailp) *tailp = tailv;
}

__global__ __launch_bounds__(256) void gscan3_k(int* __restrict__ out,
                                                const int* __restrict__ bpre, int n) {
    int idx = blockIdx.x * 256 + threadIdx.x;
    if (idx < n) out[idx] += bpre[blockIdx.x];
}

// partition edges into bucket regions: packed = (dstLocal<<17) | src
__global__ __launch_bounds__(256) void part_k(const int* __restrict__ ei,
                                              const int* __restrict__ gbase,
                                              int* __restrict__ packed) {
    __shared__ int cur[NBUK];
    __shared__ int baseL[NBUK];
    int c = blockIdx.x, t = threadIdx.x;
    for (int i = t; i < NBUK; i += 256) {
        cur[i] = 0;
        baseL[i] = gbase[i * NCH + c];
    }
    __syncthreads();
    int e0 = c * CHK;
    int e1 = min(ET, e0 + CHK);
    for (int e = e0 + t; e < e1; e += 256) {
        int src, dst;
        if (e < NE) { src = ei[e]; dst = ei[NE + e]; }
        else        { src = dst = e - NE; }
        int b = dst / BS;
        int r = atomicAdd(&cur[b], 1);
        packed[baseL[b] + r] = ((dst - b * BS) << 17) | src;
    }
}

// per-bucket counting sort -> offsets + csr (all writes confined to one XCD's L2)
__global__ __launch_bounds__(256) void csr_k(const int* __restrict__ packed,
                                             const int* __restrict__ gbase,
                                             int* __restrict__ csr,
                                             int* __restrict__ offsets) {
    __shared__ int cnt[BS];
    __shared__ int sc[2][512];
    __shared__ int cur[BS];
    __shared__ int Ss, Ts;
    int b = blockIdx.x, t = threadIdx.x;
    for (int i = t; i < BS; i += 256) cnt[i] = 0;
    if (t == 0) {
        Ss = gbase[b * NCH];
        Ts = (b == NBUK - 1) ? ET : gbase[(b + 1) * NCH];
    }
    __syncthreads();
    int n0 = Ss, n1 = Ts;
    for (int i = n0 + t; i < n1; i += 256) {
        int p = packed[i];
        atomicAdd(&cnt[p >> 17], 1);
    }
    __syncthreads();
    for (int i = t; i < 512; i += 256) sc[0][i] = (i < BS) ? cnt[i] : 0;
    __syncthreads();
    int pp = 0;
    for (int d = 1; d < 512; d <<= 1) {
        for (int i = t; i < 512; i += 256) {
            int v = sc[pp][i];
            if (i >= d) v += sc[pp][i - d];
            sc[pp ^ 1][i] = v;
        }
        pp ^= 1;
        __syncthreads();
    }
    for (int i = t; i < BS; i += 256) {
        int pre = (i == 0) ? 0 : sc[pp][i - 1];
        offsets[b * BS + i] = Ss + pre;
        cur[i] = Ss + pre;
    }
    __syncthreads();
    for (int i = n0 + t; i < n1; i += 256) {
        int p = packed[i];
        int pos = atomicAdd(&cur[p >> 17], 1);
        csr[pos] = p & 0x1FFFF;
    }
}

// deterministic order: one WAVE per node, bitonic sort across 64 lanes.
__global__ __launch_bounds__(256) void sortw_k(const int* __restrict__ offsets,
                                               int* __restrict__ csr) {
    int gt = blockIdx.x * blockDim.x + threadIdx.x;
    int n = gt >> 6;
    int lane = gt & 63;
    if (n >= NN) return;
    int b0 = offsets[n], b1 = offsets[n + 1];
    int deg = b1 - b0;
    if (deg <= 1) return;
    if (deg <= 64) {
        int v = (lane < deg) ? csr[b0 + lane] : 0x7FFFFFFF;
#pragma unroll
        for (int k = 2; k <= 64; k <<= 1) {
#pragma unroll
            for (int j = k >> 1; j > 0; j >>= 1) {
                int partner = __shfl_xor(v, j);
                bool up = ((lane & k) == 0);
                bool keepmin = (((lane & j) == 0) == up);
                v = keepmin ? min(v, partner) : max(v, partner);
            }
        }
        if (lane < deg) csr[b0 + lane] = v;
    } else if (lane == 0) {
        for (int i = b0 + 1; i < b1; i++) {
            int v = csr[i];
            int j = i - 1;
            while (j >= b0 && csr[j] > v) { csr[j + 1] = csr[j]; j--; }
            csr[j + 1] = v;
        }
    }
}

// ---------------- layer-1 alS/alD (round-5 feat1_k numerics; 2 nodes/block) ----------------

__global__ __launch_bounds__(256) void feat1b_k(const float* __restrict__ x,
                                                const float* __restrict__ w1,
                                                const float* __restrict__ as1,
                                                const float* __restrict__ ad1,
                                                float* __restrict__ alS,
                                                float* __restrict__ alD) {
    int t = threadIdx.x;
    int tt = t & 127;
    int n = blockIdx.x * 2 + (t >> 7);
    float x0 = x[n * 2 + 0], x1 = x[n * 2 + 1];
    float v = x0 * w1[tt] + x1 * w1[128 + tt];
    int head = (t >> 6) & 1, lane = t & 63;
    float ps = v * as1[tt];
    float pd = v * ad1[tt];
    for (int d = 32; d; d >>= 1) {
        ps += __shfl_down(ps, d);
        pd += __shfl_down(pd, d);
    }
    if (lane == 0) {
        alS[n * 2 + head] = ps;
        alD[n * 2 + head] = pd;
    }
}

// ---------------- fused layer 1: ONE wave per node, both heads ----------------

__global__ __launch_bounds__(256) void agg1_k(const float2* __restrict__ x2,
                                              const float* __restrict__ w1,
                                              const float* __restrict__ alS,
                                              const float* __restrict__ alD,
                                              const float* __restrict__ bias,
                                              const int* __restrict__ offsets,
                                              const int* __restrict__ csr,
                                              float* __restrict__ out) {
    __shared__ float4 wslds[4][64];
    int t = threadIdx.x;
    int wave = t >> 6, lane = t & 63, grp = lane >> 4, c4 = lane & 15;
    int gl = lane & 15;
    int n = blockIdx.x * 4 + wave;          // one node per wave
    int b0 = offsets[n], b1 = offsets[n + 1];
    int deg = b1 - b0;
    float2 adv = ((const float2*)alD)[n];   // ad0, ad1
    const float2* alS2 = (const float2*)alS;

    float4 wa0 = ((const float4*)w1)[c4];
    float4 wa1 = ((const float4*)w1)[16 + c4];
    float4 wb0 = ((const float4*)(w1 + 128))[c4];
    float4 wb1 = ((const float4*)(w1 + 128))[16 + c4];
    float4 acc0 = make_float4(0.f, 0.f, 0.f, 0.f);
    float4 acc1 = make_float4(0.f, 0.f, 0.f, 0.f);
    float inv0, inv1;

    if (deg <= 64) {
        bool valid = lane < deg;
        int s = 0; float ev0 = -1e30f, ev1 = -1e30f;
        if (valid) {
            s = csr[b0 + lane];
            float2 al = alS2[s];
            float e0 = al.x + adv.x;
            ev0 = e0 > 0.f ? e0 : 0.2f * e0;
            float e1 = al.y + adv.y;
            ev1 = e1 > 0.f ? e1 : 0.2f * e1;
        }
        float m0 = ev0, m1 = ev1;
#pragma unroll
        for (int d = 32; d; d >>= 1) {
            m0 = fmaxf(m0, __shfl_xor(m0, d));
            m1 = fmaxf(m1, __shfl_xor(m1, d));
        }
        if (valid) {
            float w0 = expf(ev0 - m0);
            float w1v = expf(ev1 - m1);
            wslds[wave][lane] = make_float4(w0, w1v, __int_as_float(s), 0.f);
        }
        float ssum0 = 0.f, ssum1 = 0.f;
#pragma unroll
        for (int k = 0; k < 4; k++) {
            int j = gl + 16 * k;
            if (j < deg) {
                float4 f = wslds[wave][j];
                ssum0 += f.x;
                ssum1 += f.y;
            }
        }
        for (int d = 8; d; d >>= 1) {
            ssum0 += __shfl_xor(ssum0, d);
            ssum1 += __shfl_xor(ssum1, d);
        }
        inv0 = 1.f / (ssum0 + 1e-16f);
        inv1 = 1.f / (ssum1 + 1e-16f);
        int j = grp;
        for (; j + 4 < deg; j += 8) {
            float4 fa = wslds[wave][j];
            float4 fb = wslds[wave][j + 4];
            float2 xa = x2[__float_as_int(fa.z)];
            float2 xb = x2[__float_as_int(fb.z)];
            float4 v0, v1;
            v0.x = xa.x * wa0.x + xa.y * wb0.x;
            v0.y = xa.x * wa0.y + xa.y * wb0.y;
            v0.z = xa.x * wa0.z + xa.y * wb0.z;
            v0.w = xa.x * wa0.w + xa.y * wb0.w;
            v1.x = xa.x * wa1.x + xa.y * wb1.x;
            v1.y = xa.x * wa1.y + xa.y * wb1.y;
            v1.z = xa.x * wa1.z + xa.y * wb1.z;
            v1.w = xa.x * wa1.w + xa.y * wb1.w;
            acc0.x = fmaf(fa.x, v0.x, acc0.x);
            acc0.y = fmaf(fa.x, v0.y, acc0.y);
            acc0.z = fmaf(fa.x, v0.z, acc0.z);
            acc0.w = fmaf(fa.x, v0.w, acc0.w);
            acc1.x = fmaf(fa.y, v1.x, acc1.x);
            acc1.y = fmaf(fa.y, v1.y, acc1.y);
            acc1.z = fmaf(fa.y, v1.z, acc1.z);
            acc1.w = fmaf(fa.y, v1.w, acc1.w);
            v0.x = xb.x * wa0.x + xb.y * wb0.x;
            v0.y = xb.x * wa0.y + xb.y * wb0.y;
            v0.z = xb.x * wa0.z + xb.y * wb0.z;
            v0.w = xb.x * wa0.w + xb.y * wb0.w;
            v1.x = xb.x * wa1.x + xb.y * wb1.x;
            v1.y = xb.x * wa1.y + xb.y * wb1.y;
            v1.z = xb.x * wa1.z + xb.y * wb1.z;
            v1.w = xb.x * wa1.w + xb.y * wb1.w;
            acc0.x = fmaf(fb.x, v0.x, acc0.x);
            acc0.y = fmaf(fb.x, v0.y, acc0.y);
            acc0.z = fmaf(fb.x, v0.z, acc0.z);
            acc0.w = fmaf(fb.x, v0.w, acc0.w);
            acc1.x = fmaf(fb.y, v1.x, acc1.x);
            acc1.y = fmaf(fb.y, v1.y, acc1.y);
            acc1.z = fmaf(fb.y, v1.z, acc1.z);
            acc1.w = fmaf(fb.y, v1.w, acc1.w);
        }
        if (j < deg) {
            float4 fa = wslds[wave][j];
            float2 xa = x2[__float_as_int(fa.z)];
            float4 v0, v1;
            v0.x = xa.x * wa0.x + xa.y * wb0.x;
            v0.y = xa.x * wa0.y + xa.y * wb0.y;
            v0.z = xa.x * wa0.z + xa.y * wb0.z;
            v0.w = xa.x * wa0.w + xa.y * wb0.w;
            v1.x = xa.x * wa1.x + xa.y * wb1.x;
            v1.y = xa.x * wa1.y + xa.y * wb1.y;
            v1.z = xa.x * wa1.z + xa.y * wb1.z;
            v1.w = xa.x * wa1.w + xa.y * wb1.w;
            acc0.x = fmaf(fa.x, v0.x, acc0.x);
            acc0.y = fmaf(fa.x, v0.y, acc0.y);
            acc0.z = fmaf(fa.x, v0.z, acc0.z);
            acc0.w = fmaf(fa.x, v0.w, acc0.w);
            acc1.x = fmaf(fa.y, v1.x, acc1.x);
            acc1.y = fmaf(fa.y, v1.y, acc1.y);
            acc1.z = fmaf(fa.y, v1.z, acc1.z);
            acc1.w = fmaf(fa.y, v1.w, acc1.w);
        }
    } else {
        for (int head = 0; head < 2; head++) {
            float ad = head ? adv.y : adv.x;
            float4 wa = head ? wa1 : wa0, wb = head ? wb1 : wb0;
            float m = -1e30f;
            for (int i = b0 + gl; i < b1; i += 16) {
                int s = csr[i];
                float ev = alS[s * 2 + head] + ad;
                ev = ev > 0.f ? ev : 0.2f * ev;
                m = fmaxf(m, ev);
            }
            for (int d = 8; d; d >>= 1) m = fmaxf(m, __shfl_xor(m, d));
            float ssum = 0.f;
            for (int i = b0 + gl; i < b1; i += 16) {
                int s = csr[i];
                float ev = alS[s * 2 + head] + ad;
                ev = ev > 0.f ? ev : 0.2f * ev;
                float w = expf(ev - m);
                ssum += w;
            }
            for (int d = 8; d; d >>= 1) ssum += __shfl_xor(ssum, d);
            float invh = 1.f / (ssum + 1e-16f);
            float4 acc = make_float4(0.f, 0.f, 0.f, 0.f);
            for (int i = b0 + grp; i < b1; i += 4) {
                int s = csr[i];
                float ev = alS[s * 2 + head] + ad;
                ev = ev > 0.f ? ev : 0.2f * ev;
                float w = expf(ev - m);
                float2 xs = x2[s];
                float4 v;
                v.x = xs.x * wa.x + xs.y * wb.x;
                v.y = xs.x * wa.y + xs.y * wb.y;
                v.z = xs.x * wa.z + xs.y * wb.z;
                v.w = xs.x * wa.w + xs.y * wb.w;
                acc.x = fmaf(w, v.x, acc.x);
                acc.y = fmaf(w, v.y, acc.y);
                acc.z = fmaf(w, v.z, acc.z);
                acc.w = fmaf(w, v.w, acc.w);
            }
            if (head == 0) { acc0 = acc; inv0 = invh; }
            else           { acc1 = acc; inv1 = invh; }
        }
    }
#pragma unroll
    for (int mask = 16; mask <= 32; mask <<= 1) {
        acc0.x += __shfl_xor(acc0.x, mask);
        acc0.y += __shfl_xor(acc0.y, mask);
        acc0.z += __shfl_xor(acc0.z, mask);
        acc0.w += __shfl_xor(acc0.w, mask);
        acc1.x += __shfl_xor(acc1.x, mask);
        acc1.y += __shfl_xor(acc1.y, mask);
        acc1.z += __shfl_xor(acc1.z, mask);
        acc1.w += __shfl_xor(acc1.w, mask);
    }
    if (grp < 2) {
        float4 acc = (grp == 0) ? acc0 : acc1;
        float inv = (grp == 0) ? inv0 : inv1;
        float4 b = ((const float4*)bias)[grp * 16 + c4];
        float4 r;
        r.x = acc.x * inv + b.x;
        r.y = acc.y * inv + b.y;
        r.z = acc.z * inv + b.z;
        r.w = acc.w * inv + b.w;
        r.x = r.x > 0.f ? r.x : expm1f(r.x);
        r.y = r.y > 0.f ? r.y : expm1f(r.y);
        r.z = r.z > 0.f ? r.z : expm1f(r.z);
        r.w = r.w > 0.f ? r.w : expm1f(r.w);
        ((float4*)out)[((size_t)n * 2 + grp) * 16 + c4] = r;
    }
}

// ---------------- GEMM + al for layers 2/3: 4 nodes/wave, 16 nodes/block ----------------

template <int K>
__global__ __launch_bounds__(256) void gemm_al_k(const float* __restrict__ in,
                                                 const float* __restrict__ W,
                                                 const float* __restrict__ as,
                                                 const float* __restrict__ ad,
                                                 float* __restrict__ h,
                                                 float* __restrict__ alS,
                                                 float* __restrict__ alD) {
    __shared__ float Wl[K * 64];
    __shared__ float rowb[16][K];
    int t = threadIdx.x;
    for (int i = t; i < K * 64; i += 256) Wl[i] = W[i];
    int wave = t >> 6, c = t & 63;
    int nb = blockIdx.x * 16 + wave * 4;
#pragma unroll
    for (int r = 0; r < 4; r++) {
        const float* row = in + (size_t)(nb + r) * K;
        for (int k = c; k < K; k += 64) rowb[wave * 4 + r][k] = row[k];
    }
    __syncthreads();
    const float* rb0 = rowb[wave * 4 + 0];
    const float* rb1 = rowb[wave * 4 + 1];
    const float* rb2 = rowb[wave * 4 + 2];
    const float* rb3 = rowb[wave * 4 + 3];
    float a0 = 0.f, a1 = 0.f, a2 = 0.f, a3 = 0.f;
#pragma unroll 4
    for (int k = 0; k < K; k++) {
        float wv = Wl[k * 64 + c];
        a0 = fmaf(rb0[k], wv, a0);
        a1 = fmaf(rb1[k], wv, a1);
        a2 = fmaf(rb2[k], wv, a2);
        a3 = fmaf(rb3[k], wv, a3);
    }
    h[(size_t)(nb + 0) * 64 + c] = a0;
    h[(size_t)(nb + 1) * 64 + c] = a1;
    h[(size_t)(nb + 2) * 64 + c] = a2;
    h[(size_t)(nb + 3) * 64 + c] = a3;
    float asc = as[c], adc = ad[c];
    float ps0 = a0 * asc, pd0 = a0 * adc;
    float ps1 = a1 * asc, pd1 = a1 * adc;
    float ps2 = a2 * asc, pd2 = a2 * adc;
    float ps3 = a3 * asc, pd3 = a3 * adc;
    for (int d = 32; d; d >>= 1) {
        ps0 += __shfl_down(ps0, d); pd0 += __shfl_down(pd0, d);
        ps1 += __shfl_down(ps1, d); pd1 += __shfl_down(pd1, d);
        ps2 += __shfl_down(ps2, d); pd2 += __shfl_down(pd2, d);
        ps3 += __shfl_down(ps3, d); pd3 += __shfl_down(pd3, d);
    }
    if (c == 0) {
        alS[nb + 0] = ps0; alD[nb + 0] = pd0;
        alS[nb + 1] = ps1; alD[nb + 1] = pd1;
        alS[nb + 2] = ps2; alD[nb + 2] = pd2;
        alS[nb + 3] = ps3; alD[nb + 3] = pd3;
    }
}

// ---------------- fused layers 2/3: 64-lane alpha + unroll-4 h4 gather agg ----------------

__global__ __launch_bounds__(256) void aggf2_k(const float4* __restrict__ h4,
                                               const float* __restrict__ alS,
                                               const float* __restrict__ alD,
                                               const float* __restrict__ bias,
                                               const int* __restrict__ offsets,
                                               const int* __restrict__ csr,
                                               float* __restrict__ out) {
    __shared__ float2 wlds[4][64];          // {w, s_bits}
    int t = threadIdx.x;
    int wave = t >> 6, lane = t & 63, grp = lane >> 4, c4 = lane & 15;
    int gl = lane & 15;
    int n = blockIdx.x * 4 + wave;
    int b0 = offsets[n], b1 = offsets[n + 1];
    int deg = b1 - b0;
    float adn = alD[n];

    float4 acc = make_float4(0.f, 0.f, 0.f, 0.f);
    float inv;

    if (deg <= 64) {
        bool valid = lane < deg;
        int s = 0; float ev = -1e30f;
        if (valid) {
            s = csr[b0 + lane];
            float e0 = alS[s] + adn;
            ev = e0 > 0.f ? e0 : 0.2f * e0;
        }
        float m = ev;
#pragma unroll
        for (int d = 32; d; d >>= 1) m = fmaxf(m, __shfl_xor(m, d));
        if (valid) {
            float w = expf(ev - m);
            wlds[wave][lane] = make_float2(w, __int_as_float(s));
        }
        float ssum = 0.f;
#pragma unroll
        for (int k = 0; k < 4; k++) {
            int j = gl + 16 * k;
            if (j < deg) ssum += wlds[wave][j].x;
        }
        for (int d = 8; d; d >>= 1) ssum += __shfl_xor(ssum, d);
        inv = 1.f / (ssum + 1e-16f);
        int j = grp;
        for (; j + 12 < deg; j += 16) {
            float2 f0 = wlds[wave][j];
            float2 f1 = wlds[wave][j + 4];
            float2 f2 = wlds[wave][j + 8];
            float2 f3 = wlds[wave][j + 12];
            float4 v0 = h4[(size_t)__float_as_int(f0.y) * 16 + c4];
            float4 v1 = h4[(size_t)__float_as_int(f1.y) * 16 + c4];
            float4 v2 = h4[(size_t)__float_as_int(f2.y) * 16 + c4];
            float4 v3 = h4[(size_t)__float_as_int(f3.y) * 16 + c4];
            acc.x = fmaf(f0.x, v0.x, acc.x);
            acc.y = fmaf(f0.x, v0.y, acc.y);
            acc.z = fmaf(f0.x, v0.z, acc.z);
            acc.w = fmaf(f0.x, v0.w, acc.w);
            acc.x = fmaf(f1.x, v1.x, acc.x);
            acc.y = fmaf(f1.x, v1.y, acc.y);
            acc.z = fmaf(f1.x, v1.z, acc.z);
            acc.w = fmaf(f1.x, v1.w, acc.w);
            acc.x = fmaf(f2.x, v2.x, acc.x);
            acc.y = fmaf(f2.x, v2.y, acc.y);
            acc.z = fmaf(f2.x, v2.z, acc.z);
            acc.w = fmaf(f2.x, v2.w, acc.w);
            acc.x = fmaf(f3.x, v3.x, acc.x);
            acc.y = fmaf(f3.x, v3.y, acc.y);
            acc.z = fmaf(f3.x, v3.z, acc.z);
            acc.w = fmaf(f3.x, v3.w, acc.w);
        }
        for (; j < deg; j += 4) {
            float2 f0 = wlds[wave][j];
            float4 v0 = h4[(size_t)__float_as_int(f0.y) * 16 + c4];
            acc.x = fmaf(f0.x, v0.x, acc.x);
            acc.y = fmaf(f0.x, v0.y, acc.y);
            acc.z = fmaf(f0.x, v0.z, acc.z);
            acc.w = fmaf(f0.x, v0.w, acc.w);
        }
    } else {
        float m = -1e30f;
        for (int i = b0 + gl; i < b1; i += 16) {
            int s = csr[i];
            float ev = alS[s] + adn;
            ev = ev > 0.f ? ev : 0.2f * ev;
            m = fmaxf(m, ev);
        }
        for (int d = 8; d; d >>= 1) m = fmaxf(m, __shfl_xor(m, d));
        float ssum = 0.f;
        for (int i = b0 + gl; i < b1; i += 16) {
            int s = csr[i];
            float ev = alS[s] + adn;
            ev = ev > 0.f ? ev : 0.2f * ev;
            float w = expf(ev - m);
            ssum += w;
        }
        for (int d = 8; d; d >>= 1) ssum += __shfl_xor(ssum, d);
        inv = 1.f / (ssum + 1e-16f);
        for (int i = b0 + grp; i < b1; i += 4) {
            int s = csr[i];
            float ev = alS[s] + adn;
            ev = ev > 0.f ? ev : 0.2f * ev;
            float w = expf(ev - m);
            float4 v = h4[(size_t)s * 16 + c4];
            acc.x = fmaf(w, v.x, acc.x);
            acc.y = fmaf(w, v.y, acc.y);
            acc.z = fmaf(w, v.z, acc.z);
            acc.w = fmaf(w, v.w, acc.w);
        }
    }
#pragma unroll
    for (int mask = 16; mask <= 32; mask <<= 1) {
        acc.x += __shfl_xor(acc.x, mask);
        acc.y += __shfl_xor(acc.y, mask);
        acc.z += __shfl_xor(acc.z, mask);
        acc.w += __shfl_xor(acc.w, mask);
    }
    if (grp == 0) {
        float4 b = ((const float4*)bias)[c4];
        float4 r;
        r.x = acc.x * inv + b.x;
        r.y = acc.y * inv + b.y;
        r.z = acc.z * inv + b.z;
        r.w = acc.w * inv + b.w;
        r.x = r.x > 0.f ? r.x : expm1f(r.x);
        r.y = r.y > 0.f ? r.y : expm1f(r.y);
        r.z = r.z > 0.f ? r.z : expm1f(r.z);
        r.w = r.w > 0.f ? r.w : expm1f(r.w);
        ((float4*)out)[(size_t)n * 16 + c4] = r;
    }
}

// ---------------- global mean pool (batch sorted) ----------------

__global__ __launch_bounds__(1024) void pool_k(const float* __restrict__ h,
                                               const int* __restrict__ batch,
                                               float* __restrict__ gout) {
    int g = blockIdx.x;
    __shared__ int sb, se;
    __shared__ float partial[16][64];
    int t = threadIdx.x, wave = t >> 6, c = t & 63;
    if (t == 0) {
        int lo = 0, hi = NN;
        while (lo < hi) { int mid = (lo + hi) >> 1; if (batch[mid] < g) lo = mid + 1; else hi = mid; }
        sb = lo;
        lo = 0; hi = NN;
        while (lo < hi) { int mid = (lo + hi) >> 1; if (batch[mid] < g + 1) lo = mid + 1; else hi = mid; }
        se = lo;
    }
    __syncthreads();
    float acc = 0.f;
    for (int r = sb + wave; r < se; r += 16) acc += h[(size_t)r * 64 + c];
    partial[wave][c] = acc;
    __syncthreads();
    if (wave == 0) {
        float s = 0.f;
#pragma unroll
        for (int wv = 0; wv < 16; wv++) s += partial[wv][c];
        int cnt = se - sb;
        gout[g * 64 + c] = s / fmaxf((float)cnt, 1.0f);
    }
}

// ---------------- MLP head ----------------

__global__ __launch_bounds__(64) void mlp_k(const float* __restrict__ g,
                                            const float* __restrict__ fw1,
                                            const float* __restrict__ fb1,
                                            const float* __restrict__ fw2,
                                            const float* __restrict__ fb2,
                                            float* __restrict__ out) {
    int gi = blockIdx.x;
    __shared__ float gv[64];
    __shared__ float hid[32];
    int t = threadIdx.x;
    gv[t] = g[gi * 64 + t];
    __syncthreads();
    if (t < 32) {
        float a = fb1[t];
        for (int c = 0; c < 64; c++) a += gv[c] * fw1[c * 32 + t];
        hid[t] = a > 0.f ? a : 0.f;
    }
    __syncthreads();
    if (t == 0) {
        float o = fb2[0];
        for (int j = 0; j < 32; j++) o += hid[j] * fw2[j];
        out[gi] = o;
    }
}

// ---------------- launch ----------------

extern "C" void kernel_launch(void* const* d_in, const int* in_sizes, int n_in,
                              void* d_out, int out_size, void* d_ws, size_t ws_size,
                              hipStream_t stream) {
    const float* x   = (const float*)d_in[0];
    const int*   ei  = (const int*)d_in[1];
    const int*   bat = (const int*)d_in[2];
    const float* w1  = (const float*)d_in[3];
    const float* as1 = (const float*)d_in[4];
    const float* ad1 = (const float*)d_in[5];
    const float* b1  = (const float*)d_in[6];
    const float* w2  = (const float*)d_in[7];
    const float* as2 = (const float*)d_in[8];
    const float* ad2 = (const float*)d_in[9];
    const float* b2  = (const float*)d_in[10];
    const float* w3  = (const float*)d_in[11];
    const float* as3 = (const float*)d_in[12];
    const float* ad3 = (const float*)d_in[13];
    const float* b3  = (const float*)d_in[14];
    const float* fw1 = (const float*)d_in[15];
    const float* fb1 = (const float*)d_in[16];
    const float* fw2 = (const float*)d_in[17];
    const float* fb2 = (const float*)d_in[18];
    float* out = (float*)d_out;

    char* ws = (char*)d_ws;
    size_t o = 0;
    auto alloc = [&](size_t bytes) -> void* {
        void* p = ws + o;
        o += (bytes + 255) & ~(size_t)255;
        return p;
    };
    int*    offsets = (int*)alloc((NN + 1) * sizeof(int));
    int*    ghist   = (int*)alloc(NHIST * sizeof(int));
    int*    gbase   = (int*)alloc(NHIST * sizeof(int));
    int*    bsum    = (int*)alloc(NSB * sizeof(int));
    int*    bpre    = (int*)alloc(NSB * sizeof(int));
    int*    packed  = (int*)alloc(ET * sizeof(int));
    int*    csr     = (int*)alloc(ET * sizeof(int));
    float*  l1out   = (float*)alloc((size_t)NN * 128 * sizeof(float));
    float*  hX      = (float*)alloc((size_t)NN * 64 * sizeof(float));
    float*  l2out   = (float*)alloc((size_t)NN * 64 * sizeof(float));
    float*  l3out   = (float*)alloc((size_t)NN * 64 * sizeof(float));
    float*  alS     = (float*)alloc((size_t)NN * 2 * sizeof(float));
    float*  alD     = (float*)alloc((size_t)NN * 2 * sizeof(float));
    float*  gbuf    = (float*)alloc((size_t)NG * 64 * sizeof(float));

    // CSR build: bucket partition (deterministic content; sortw canonicalizes order)
    hist_k<<<NCH, 256, 0, stream>>>(ei, ghist);
    gscan1_k<<<NSB, 256, 0, stream>>>(ghist, gbase, bsum, NHIST);
    gscan2_k<<<1, 256, 0, stream>>>(bsum, bpre, NSB, offsets + NN, ET);
    gscan3_k<<<NSB, 256, 0, stream>>>(gbase, bpre, NHIST);
    part_k<<<NCH, 256, 0, stream>>>(ei, gbase, packed);
    csr_k<<<NBUK, 256, 0, stream>>>(packed, gbase, csr, offsets);
    sortw_k<<<NN / 4, 256, 0, stream>>>(offsets, csr);

    // layer 1: alS/alD then fused alpha+agg, one wave per node, both heads
    feat1b_k<<<NN / 2, 256, 0, stream>>>(x, w1, as1, ad1, alS, alD);
    agg1_k<<<NN / 4, 256, 0, stream>>>((const float2*)x, w1, alS, alD, b1, offsets, csr, l1out);

    // layer 2: 128 -> 64
    gemm_al_k<128><<<NN / 16, 256, 0, stream>>>(l1out, w2, as2, ad2, hX, alS, alD);
    aggf2_k<<<NN / 4, 256, 0, stream>>>((const float4*)hX, alS, alD, b2, offsets, csr, l2out);

    // layer 3: 64 -> 64
    gemm_al_k<64><<<NN / 16, 256, 0, stream>>>(l2out, w3, as3, ad3, hX, alS, alD);
    aggf2_k<<<NN / 4, 256, 0, stream>>>((const float4*)hX, alS, alD, b3, offsets, csr, l3out);

    // pool + MLP head
    pool_k<<<NG, 1024, 0, stream>>>(l3out, bat, gbuf);
    mlp_k<<<NG, 64, 0, stream>>>(gbuf, fw1, fb1, fw2, fb2, out);
}